// Round 14
// baseline (312.620 us; speedup 1.0000x reference)
//
#include <hip/hip_runtime.h>
#include <math.h>

#define N_ATOMS 50000
#define IN_DIM 128
#define HID 256
#define N_ELEM 4
#define N_IMG 500
#define NNZ 2000000

// R27: 5 blocks/CU. Fused tile stride 40 -> 32 with XOR swizzle
// (col ^= ((row>>2)&3)<<3 on 16B slots: 16 lanes -> 8 banks -> 2-way = free).
// tH+tD = 2x16384 = 32768 B; 5 x 32768 = 160 KiB exactly. Energy partials
// move from pad cols (gone) to VGPRs -> tD chunk 4 (dead after e3 barrier).
// Producer PCH 2304 to fit the same 32768 B union.
#define CBINS 293        // col >> 9 over 150,016 cols
#define CW 512           // cols per bin (2 KB LDS window)
#define BCAP 8192        // expect 6826 +- 83 (16 sigma headroom)
#define OCAP 4096        // overflow list capacity (expected use: 0)
#define PCH 2304         // producer chunk (12*2304 + 4688 = 32,336 B LDS)
#define NBP ((NNZ + PCH - 1) / PCH)   // 869 producer blocks
#define TILES_PER_E 416  // 32-row tiles; covers mean+8.4sigma atoms/element
#define NFB (8 * (TILES_PER_E / 2))   // 1664 fused blocks
#define TOTB (NBP + NFB)              // 2533 mega blocks
#define BKB ((N_ATOMS + 255) / 256)   // 196 bucket blocks
#define PREPB 384                     // prep blocks

// LDS swizzle: XOR the 16B-slot bits of the short-col with row bits 2-3.
#define SWZ(row, col) ((col) ^ ((((row) >> 2) & 3) << 3))

typedef __attribute__((ext_vector_type(8))) short bf16x8;   // 8 bf16 = 4 VGPRs
typedef __attribute__((ext_vector_type(4))) float f32x4;    // MFMA C/D frag
typedef __attribute__((ext_vector_type(4))) int   i32x4;    // native vec loads
typedef __attribute__((ext_vector_type(4))) float fv4;      // native vec loads

__device__ __forceinline__ int elem_of(int z) {
    return (z == 1) ? 0 : (z == 6) ? 1 : (z == 8) ? 2 : 3;
}

__device__ __forceinline__ unsigned short f2bf(float f) {   // RNE
    unsigned u = __float_as_uint(f);
    u += 0x7fffu + ((u >> 16) & 1u);
    return (unsigned short)(u >> 16);
}
__device__ __forceinline__ float bf2f(unsigned short u) {
    return __uint_as_float(((unsigned)u) << 16);
}
__device__ __forceinline__ float tanh_fast(float x) {
    float e = __expf(2.f * x);
    return (e - 1.f) / (e + 1.f);
}

// ---------------------------------------------------------------------------
// K1) prep_weights + bucket_atoms in one dispatch (R22). Unchanged.
// ---------------------------------------------------------------------------
__global__ __launch_bounds__(256) void prep_and_bucket(
    const float* __restrict__ W0, const float* __restrict__ W1,
    unsigned short* __restrict__ W0s1,   // stage1: Bt[h][d], K=128, KN=4
    unsigned short* __restrict__ W1s2,   // stage2: Bt[h1][h0], K=256, KN=8
    unsigned short* __restrict__ W1s3,   // stage3: Bt[h0][h1], K=256, KN=8
    unsigned short* __restrict__ W0s4,   // stage4: Bt[d][h], K=256, KN=8
    const int* __restrict__ Z, int* __restrict__ counts,
    int* __restrict__ lists, float* __restrict__ F) {

    const int tid = threadIdx.x;

    if (blockIdx.x >= PREPB) {
        // ----- atom bucketing + F zeroing -----
        __shared__ int lcnt[N_ELEM], lbase[N_ELEM];
        const int bb = blockIdx.x - PREPB;
        for (int idx = bb * 256 + tid; idx < 3 * N_ATOMS; idx += BKB * 256)
            F[idx] = 0.f;
        const int i = bb * 256 + tid;
        if (tid < N_ELEM) lcnt[tid] = 0;
        __syncthreads();
        int e = -1, pos = 0;
        if (i < N_ATOMS) {
            e = elem_of(Z[i]);
            pos = atomicAdd(&lcnt[e], 1);
        }
        __syncthreads();
        if (tid < N_ELEM) lbase[tid] = atomicAdd(&counts[tid], lcnt[tid]);
        __syncthreads();
        if (i < N_ATOMS) lists[e * N_ATOMS + lbase[e] + pos] = i;
        return;
    }

    const int T = blockIdx.x * 256 + tid;   // [0, 98304)

    if (T < 32768) {
        // W1s2: row=n(h1), col=k(h0). frag spans k&7; k-gather stride 256.
        const int e = T >> 13, fid = T & 8191;
        const int blkv = fid >> 6, lane = fid & 63;
        const int k0 = ((blkv & 7) << 5) | ((lane >> 4) << 3);
        const int n  = ((blkv >> 3) << 4) | (lane & 15);
        const float* src = W1 + e * 65536 + n;
        bf16x8 vv;
#pragma unroll
        for (int j = 0; j < 8; ++j) vv[j] = (short)f2bf(src[(k0 + j) * 256]);
        *(bf16x8*)(W1s2 + (e << 16) + (fid << 3)) = vv;
    } else if (T < 65536) {
        // W1s3: row=k(h0), col=n(h1). frag spans n&7 -> 8 contiguous floats.
        const int u = T - 32768, e = u >> 13, fid = u & 8191;
        const int blkv = fid >> 6, lane = fid & 63;
        const int k  = ((blkv >> 3) << 4) | (lane & 15);
        const int n0 = ((blkv & 7) << 5) | ((lane >> 4) << 3);
        const float* src = W1 + e * 65536 + k * 256 + n0;
        float4 a = *(const float4*)src;
        float4 b = *(const float4*)(src + 4);
        bf16x8 vv;
        vv[0] = (short)f2bf(a.x); vv[1] = (short)f2bf(a.y);
        vv[2] = (short)f2bf(a.z); vv[3] = (short)f2bf(a.w);
        vv[4] = (short)f2bf(b.x); vv[5] = (short)f2bf(b.y);
        vv[6] = (short)f2bf(b.z); vv[7] = (short)f2bf(b.w);
        *(bf16x8*)(W1s3 + (e << 16) + (fid << 3)) = vv;
    } else if (T < 81920) {
        // W0s1: row=n(h), col=k(d), K=128. frag spans k&7; k-gather.
        const int u = T - 65536, e = u >> 12, fid = u & 4095;
        const int blkv = fid >> 6, lane = fid & 63;
        const int k0 = ((blkv & 3) << 5) | ((lane >> 4) << 3);
        const int n  = ((blkv >> 2) << 4) | (lane & 15);
        const float* src = W0 + e * 32768 + n;
        bf16x8 vv;
#pragma unroll
        for (int j = 0; j < 8; ++j) vv[j] = (short)f2bf(src[(k0 + j) * 256]);
        *(bf16x8*)(W0s1 + e * 32768 + (fid << 3)) = vv;
    } else if (T < 98304) {
        // W0s4: row=k(d), col=n(h). frag spans n&7 -> 8 contiguous floats.
        const int u = T - 81920, e = u >> 12, fid = u & 4095;
        const int blkv = fid >> 6, lane = fid & 63;
        const int k  = ((blkv >> 3) << 4) | (lane & 15);
        const int n0 = ((blkv & 7) << 5) | ((lane >> 4) << 3);
        const float* src = W0 + e * 32768 + k * 256 + n0;
        float4 a = *(const float4*)src;
        float4 b = *(const float4*)(src + 4);
        bf16x8 vv;
        vv[0] = (short)f2bf(a.x); vv[1] = (short)f2bf(a.y);
        vv[2] = (short)f2bf(a.z); vv[3] = (short)f2bf(a.w);
        vv[4] = (short)f2bf(b.x); vv[5] = (short)f2bf(b.y);
        vv[6] = (short)f2bf(b.z); vv[7] = (short)f2bf(b.w);
        *(bf16x8*)(W0s4 + e * 32768 + (fid << 3)) = vv;
    }
}

// ---------------------------------------------------------------------------
// K2) MEGA dispatch — R27: LDS 32,768 B -> __launch_bounds__(256,5), swizzled
//     stride-32 tiles. Bresenham interleave + uint2 scatter + wave-scan kept.
// ---------------------------------------------------------------------------
#define CH 1024           // chunk stride in shorts (32*32, swizzled)
__global__ __launch_bounds__(256, 5) void mega_mlp_bin(
    // fused args
    const float* __restrict__ fp,
    const unsigned short* __restrict__ W0s1,
    const unsigned short* __restrict__ W1s2,
    const unsigned short* __restrict__ W1s3,
    const unsigned short* __restrict__ W0s4,
    const float* __restrict__ b0, const float* __restrict__ b1,
    const float* __restrict__ W2, const float* __restrict__ b2,
    float* __restrict__ o_atom,
    unsigned short* __restrict__ Gb,
    const int* __restrict__ counts, const int* __restrict__ lists,
    // producer args
    const int* __restrict__ rows, const int* __restrict__ cols,
    const float* __restrict__ vals,
    unsigned* __restrict__ pvB,
    int* __restrict__ gcur,
    int* __restrict__ ovfR, int* __restrict__ ovfC, float* __restrict__ ovfV,
    int* __restrict__ ocur) {

    __shared__ __align__(16) char smem[32768];
    const int tid = threadIdx.x;

    // Bresenham split: producers spread evenly through dispatch order.
    const int bid = blockIdx.x;
    const int pA = (bid * NBP) / TOTB;          // producers before bid
    const int pB = ((bid + 1) * NBP) / TOTB;    // producers before bid+1

    if (pB > pA) {
        // =================== COO bin producer (pidx = pA) ===================
        int*   Lr    = (int*)smem;                    // 2304*4 = 9216 B
        int*   Lc    = (int*)(smem + 9216);           // 9216 B
        float* Lv    = (float*)(smem + 18432);        // 9216 B
        int*   hist  = (int*)(smem + 27648);          // 1172 B
        int*   pref  = (int*)(smem + 28820);
        int*   curs  = (int*)(smem + 29992);
        int*   gbase = (int*)(smem + 31164);          // ends at 32336

        const int base = pA * PCH;
        const int lim = (base + PCH <= NNZ) ? PCH : (NNZ - base);

        for (int i = tid; i < CBINS; i += 256) hist[i] = 0;
        __syncthreads();

        // phase 1: stash 2304 entries (3 x int4 groups) + LDS histogram
        i32x4 r[3], c[3];
        fv4   v[3];
        int nvalid[3];
#pragma unroll
        for (int j = 0; j < 3; ++j) {
            const int li = tid * 4 + 1024 * j;
            const int i0 = base + li;
            int nv = lim - li;
            nvalid[j] = nv > 4 ? 4 : (nv < 0 ? 0 : nv);
            if (nvalid[j] == 4) {
                r[j] = __builtin_nontemporal_load((const i32x4*)(rows + i0));
                c[j] = __builtin_nontemporal_load((const i32x4*)(cols + i0));
                v[j] = __builtin_nontemporal_load((const fv4*)(vals + i0));
            } else {
                for (int e2 = 0; e2 < nvalid[j]; ++e2) {
                    r[j][e2] = rows[i0 + e2]; c[j][e2] = cols[i0 + e2];
                    v[j][e2] = vals[i0 + e2];
                }
            }
#pragma unroll
            for (int e2 = 0; e2 < 4; ++e2)
                if (e2 < nvalid[j]) atomicAdd(&hist[c[j][e2] >> 9], 1);
        }
        __syncthreads();

        // phase 2: wave-parallel exclusive prefix over 293 bins
        if (tid < 64) {
            int carry = 0;
#pragma unroll
            for (int cch = 0; cch < 5; ++cch) {
                const int i = cch * 64 + tid;
                const int h = (i < CBINS) ? hist[i] : 0;
                int x = h;
#pragma unroll
                for (int off = 1; off < 64; off <<= 1) {
                    int y = __shfl_up(x, off, 64);
                    if (tid >= off) x += y;
                }
                if (i < CBINS) pref[i] = carry + x - h;   // exclusive
                carry += __shfl(x, 63, 64);
            }
        }
        __syncthreads();
        // phase 2.5: reserve global ranges; init cursors
        for (int b = tid; b < CBINS; b += 256) {
            gbase[b] = atomicAdd(&gcur[b], hist[b]);
            curs[b] = pref[b];
        }
        __syncthreads();

        // phase 3: scatter into LDS (counting-sort order)
#pragma unroll
        for (int j = 0; j < 3; ++j)
#pragma unroll
            for (int e2 = 0; e2 < 4; ++e2)
                if (e2 < nvalid[j]) {
                    int b = c[j][e2] >> 9;
                    int p = atomicAdd(&curs[b], 1);
                    Lr[p] = r[j][e2]; Lc[p] = c[j][e2]; Lv[p] = v[j][e2];
                }
        __syncthreads();

        // phase 4: linear LDS -> global, ONE uint2 {pack,val} per entry
#pragma unroll
        for (int j = 0; j < 9; ++j) {
            const int p = tid + 256 * j;
            if (p >= lim) break;
            const int col = Lc[p];
            const int b = col >> 9;
            const int g = gbase[b] + (p - pref[b]);
            if (g < BCAP) {
                uint2 w;
                w.x = ((unsigned)(col & 511) << 23) | (unsigned)Lr[p];
                w.y = __float_as_uint(Lv[p]);
                *(uint2*)(pvB + (((size_t)b * BCAP + g) << 1)) = w;
            } else {
                int od = atomicAdd(ocur, 1);
                if (od < OCAP) { ovfR[od] = Lr[p]; ovfC[od] = col; ovfV[od] = Lv[p]; }
            }
        }
        return;
    }

    // =================== fused MLP fwd+bwd (swizzled stride-32) ============
    const int fid = bid - pB;
    const int xcd = fid & 7;
    const int e = xcd & 3;
    const int tile = (fid >> 3) * 2 + (xcd >> 2);
    const int cnt = counts[e];
    const int m0 = tile * 32;
    if (m0 >= cnt) return;
    const int* list = lists + e * N_ATOMS;

    short* tH = (short*)smem;                    // 16384 B
    short* tD = (short*)(smem + 16384);          // 16384 B (chunk4: energy red)

    const int lane = tid & 63;
    const int wv = tid >> 6;       // 0..3, n-range wv*64
    const int lr = lane & 15;
    const int lq = lane >> 4;
    const int fsw = ((lr >> 2) & 3) << 3;   // frag-read swizzle (row==lr mod 16)

    const unsigned short* B1 = W0s1 + (size_t)e * HID * IN_DIM;
    const unsigned short* B2 = W1s2 + (size_t)e * HID * HID;
    const unsigned short* B3 = W1s3 + (size_t)e * HID * HID;
    const unsigned short* B4 = W0s4 + (size_t)e * IN_DIM * HID;

    f32x4 acc[2][4];
    float osumR[2][4];             // energy partials, e2 -> e4 (lanes lr==0)
#define ZERO_ACC()                                                        \
    _Pragma("unroll") for (int mt = 0; mt < 2; ++mt)                      \
        _Pragma("unroll") for (int nt = 0; nt < 4; ++nt)                  \
            _Pragma("unroll") for (int j = 0; j < 4; ++j) acc[mt][nt][j] = 0.f;

    // ---- S1 A-tile staging ----
    {
        bf16x8 bb0[4];   // hoisted B ki=0 preload (flies during staging)
#pragma unroll
        for (int nt = 0; nt < 4; ++nt)
            bb0[nt] = *(const bf16x8*)(B1 +
                ((size_t)(((wv * 4 + nt) * 4 + 0) * 64 + lane) << 3));

#pragma unroll
        for (int p = 0; p < 4; ++p) {
            const int row = p * 8 + (tid >> 5);
            const int col = (tid & 31) * 4;          // float index in row
            const int m = m0 + row;
            float4 a = make_float4(0.f, 0.f, 0.f, 0.f);
            if (m < cnt)
                a = *(const float4*)(fp + (size_t)list[m] * IN_DIM + col);
            short4 b;
            b.x = (short)f2bf(a.x); b.y = (short)f2bf(a.y);
            b.z = (short)f2bf(a.z); b.w = (short)f2bf(a.w);
            *(short4*)&tD[(col >> 5) * CH + row * 32 + SWZ(row, col & 31)] = b;
        }
        __syncthreads();

        // =============== Stage 1: z0 = A @ W0^T  (K=128, KN=4, B ring-2) ===
        ZERO_ACC();
        bf16x8 bb[2][4];
#pragma unroll
        for (int nt = 0; nt < 4; ++nt) bb[0][nt] = bb0[nt];
#pragma unroll
        for (int ki = 0; ki < 4; ++ki) {
            const int cur = ki & 1, nx = cur ^ 1;
            if (ki < 3) {
#pragma unroll
                for (int nt = 0; nt < 4; ++nt)
                    bb[nx][nt] = *(const bf16x8*)(B1 +
                        ((size_t)(((wv * 4 + nt) * 4 + ki + 1) * 64 + lane) << 3));
            }
            bf16x8 af[2];
#pragma unroll
            for (int mt = 0; mt < 2; ++mt)
                af[mt] = *(const bf16x8*)&tD[ki * CH + (mt * 16 + lr) * 32 + (lq * 8 ^ fsw)];
#pragma unroll
            for (int mt = 0; mt < 2; ++mt)
#pragma unroll
                for (int nt = 0; nt < 4; ++nt)
                    acc[mt][nt] = __builtin_amdgcn_mfma_f32_16x16x32_bf16(
                        af[mt], bb[cur][nt], acc[mt][nt], 0, 0, 0);
        }
    }

    // S2 B-ring preload
    bf16x8 b2r[3][4];
#pragma unroll
    for (int p = 0; p < 3; ++p)
#pragma unroll
        for (int nt = 0; nt < 4; ++nt)
            b2r[p][nt] = *(const bf16x8*)(B2 +
                ((size_t)(((wv * 4 + nt) * 8 + p) * 64 + lane) << 3));

    // epilogue 1: h0 -> tH
    {
        float bv[4];
#pragma unroll
        for (int nt = 0; nt < 4; ++nt)
            bv[nt] = b0[e * HID + wv * 64 + nt * 16 + lr];
#pragma unroll
        for (int mt = 0; mt < 2; ++mt)
#pragma unroll
            for (int rr = 0; rr < 4; ++rr) {
                const int row = mt * 16 + lq * 4 + rr;
#pragma unroll
                for (int nt = 0; nt < 4; ++nt) {
                    const int n = wv * 64 + nt * 16 + lr;
                    float t = tanh_fast(acc[mt][nt][rr] + bv[nt]);
                    tH[(n >> 5) * CH + row * 32 + SWZ(row, n & 31)] = (short)f2bf(t);
                }
            }
    }
    __syncthreads();

    // =============== Stage 2: z1 = h0 @ W1^T   (K=256, ring-3) =============
    ZERO_ACC();
#pragma unroll
    for (int ki = 0; ki < 8; ++ki) {
        bf16x8 af[2];
#pragma unroll
        for (int mt = 0; mt < 2; ++mt)
            af[mt] = *(const bf16x8*)&tH[ki * CH + (mt * 16 + lr) * 32 + (lq * 8 ^ fsw)];
#pragma unroll
        for (int mt = 0; mt < 2; ++mt)
#pragma unroll
            for (int nt = 0; nt < 4; ++nt)
                acc[mt][nt] = __builtin_amdgcn_mfma_f32_16x16x32_bf16(
                    af[mt], b2r[ki % 3][nt], acc[mt][nt], 0, 0, 0);
        if (ki < 5) {
#pragma unroll
            for (int nt = 0; nt < 4; ++nt)
                b2r[ki % 3][nt] = *(const bf16x8*)(B2 +
                    ((size_t)(((wv * 4 + nt) * 8 + ki + 3) * 64 + lane) << 3));
        }
    }

    // S3 B-ring preload
    bf16x8 b3r[3][4];
#pragma unroll
    for (int p = 0; p < 3; ++p)
#pragma unroll
        for (int nt = 0; nt < 4; ++nt)
            b3r[p][nt] = *(const bf16x8*)(B3 +
                ((size_t)(((wv * 4 + nt) * 8 + p) * 64 + lane) << 3));

    // epilogue 2: dz1 -> tD; o partials -> osumR regs (written to LDS in e4)
    {
        float bv[4], w2v[4];
#pragma unroll
        for (int nt = 0; nt < 4; ++nt) {
            bv[nt]  = b1[e * HID + wv * 64 + nt * 16 + lr];
            w2v[nt] = W2[e * HID + wv * 64 + nt * 16 + lr];
        }
#pragma unroll
        for (int mt = 0; mt < 2; ++mt)
#pragma unroll
            for (int rr = 0; rr < 4; ++rr) {
                const int row = mt * 16 + lq * 4 + rr;
                float osum = 0.f;
#pragma unroll
                for (int nt = 0; nt < 4; ++nt) {
                    const int n = wv * 64 + nt * 16 + lr;
                    float t = tanh_fast(acc[mt][nt][rr] + bv[nt]);
                    osum += t * w2v[nt];
                    tD[(n >> 5) * CH + row * 32 + SWZ(row, n & 31)] =
                        (short)f2bf(w2v[nt] * (1.f - t * t));
                }
                osum += __shfl_xor(osum, 1, 64);
                osum += __shfl_xor(osum, 2, 64);
                osum += __shfl_xor(osum, 4, 64);
                osum += __shfl_xor(osum, 8, 64);
                osumR[mt][rr] = osum;          // valid on all lanes of group
            }
    }
    __syncthreads();

    // =============== Stage 3: dh0 = dz1 @ W1   (K=256, ring-3) =============
    ZERO_ACC();
#pragma unroll
    for (int ki = 0; ki < 8; ++ki) {
        bf16x8 af[2];
#pragma unroll
        for (int mt = 0; mt < 2; ++mt)
            af[mt] = *(const bf16x8*)&tD[ki * CH + (mt * 16 + lr) * 32 + (lq * 8 ^ fsw)];
#pragma unroll
        for (int mt = 0; mt < 2; ++mt)
#pragma unroll
            for (int nt = 0; nt < 4; ++nt)
                acc[mt][nt] = __builtin_amdgcn_mfma_f32_16x16x32_bf16(
                    af[mt], b3r[ki % 3][nt], acc[mt][nt], 0, 0, 0);
        if (ki < 5) {
#pragma unroll
            for (int nt = 0; nt < 4; ++nt)
                b3r[ki % 3][nt] = *(const bf16x8*)(B3 +
                    ((size_t)(((wv * 4 + nt) * 8 + ki + 3) * 64 + lane) << 3));
        }
    }

    // S4 B-ring preload
    bf16x8 b4r[3][2];
#pragma unroll
    for (int p = 0; p < 3; ++p)
#pragma unroll
        for (int nt = 0; nt < 2; ++nt)
            b4r[p][nt] = *(const bf16x8*)(B4 +
                ((size_t)(((wv * 2 + nt) * 8 + p) * 64 + lane) << 3));

    // epilogue 3: dz0 = dh0*(1-h0^2) -> tH in-place (same thread owns slot)
#pragma unroll
    for (int mt = 0; mt < 2; ++mt)
#pragma unroll
        for (int rr = 0; rr < 4; ++rr) {
            const int row = mt * 16 + lq * 4 + rr;
#pragma unroll
            for (int nt = 0; nt < 4; ++nt) {
                const int n = wv * 64 + nt * 16 + lr;
                const int a = (n >> 5) * CH + row * 32 + SWZ(row, n & 31);
                float h = bf2f((unsigned short)tH[a]);
                tH[a] = (short)f2bf(acc[mt][nt][rr] * (1.f - h * h));
            }
        }
    __syncthreads();

    // =============== Stage 4: g = dz0 @ W0   (K=256, NT=2, ring-3) =========
    {
        f32x4 a4[2][2];
#pragma unroll
        for (int mt = 0; mt < 2; ++mt)
#pragma unroll
            for (int nt = 0; nt < 2; ++nt)
#pragma unroll
                for (int j = 0; j < 4; ++j) a4[mt][nt][j] = 0.f;
#pragma unroll
        for (int ki = 0; ki < 8; ++ki) {
            bf16x8 af[2];
#pragma unroll
            for (int mt = 0; mt < 2; ++mt)
                af[mt] = *(const bf16x8*)&tH[ki * CH + (mt * 16 + lr) * 32 + (lq * 8 ^ fsw)];
#pragma unroll
            for (int mt = 0; mt < 2; ++mt)
#pragma unroll
                for (int nt = 0; nt < 2; ++nt)
                    a4[mt][nt] = __builtin_amdgcn_mfma_f32_16x16x32_bf16(
                        af[mt], b4r[ki % 3][nt], a4[mt][nt], 0, 0, 0);
            if (ki < 5) {
#pragma unroll
                for (int nt = 0; nt < 2; ++nt)
                    b4r[ki % 3][nt] = *(const bf16x8*)(B4 +
                        ((size_t)(((wv * 2 + nt) * 8 + ki + 3) * 64 + lane) << 3));
            }
        }
        // epilogue 4: g -> tD chunks 0..3; energy partials -> tD chunk 4
        //   (chunks 4..7 dead: last read in S3, barrier after e3 passed)
#pragma unroll
        for (int mt = 0; mt < 2; ++mt)
#pragma unroll
            for (int rr = 0; rr < 4; ++rr) {
                const int row = mt * 16 + lq * 4 + rr;
#pragma unroll
                for (int nt = 0; nt < 2; ++nt) {
                    const int n = wv * 32 + nt * 16 + lr;
                    tD[(n >> 5) * CH + row * 32 + SWZ(row, n & 31)] =
                        (short)f2bf(a4[mt][nt][rr]);
                }
                if (lr == 0)
                    ((float*)&tD[4 * CH])[wv * 32 + row] = osumR[mt][rr];
            }
    }
    __syncthreads();
#pragma unroll
    for (int t = 0; t < 2; ++t) {
        const int c = tid + 256 * t;         // 0..511
        const int row = c >> 4;              // 0..31
        const int pos = (c & 15) * 8;        // 0..120
        const int m = m0 + row;
        if (m < cnt) {
            bf16x8 v = *(const bf16x8*)&tD[(pos >> 5) * CH + row * 32 + SWZ(row, pos & 31)];
            *(bf16x8*)(Gb + (size_t)list[m] * IN_DIM + pos) = v;
        }
    }
    if (tid < 32) {
        int m = m0 + tid;
        if (m < cnt) {
            const float* rp = (const float*)&tD[4 * CH];
            o_atom[list[m]] = rp[tid] + rp[32 + tid] + rp[64 + tid] +
                              rp[96 + tid] + b2[e];
        }
    }
#undef ZERO_ACC
}

// ---------------------------------------------------------------------------
// K3) Forces consumer — unchanged from R25: one block per col-window,
//     unroll-8 single pass, NT pvB loads, plain F stores.
// ---------------------------------------------------------------------------
__global__ __launch_bounds__(1024) void forces_consumer(
    const unsigned* __restrict__ pvB,
    const int* __restrict__ gcur,
    const unsigned short* __restrict__ g, float* __restrict__ F,
    const float* __restrict__ o_atom, const int* __restrict__ img,
    float* __restrict__ energy,
    const int* __restrict__ ovfR, const int* __restrict__ ovfC,
    const float* __restrict__ ovfV, const int* __restrict__ ocur) {

    const int blk = blockIdx.x;
    const int tid = threadIdx.x;

    if (blk < CBINS) {
        __shared__ float win[CW];
        for (int i = tid; i < CW; i += 1024) win[i] = 0.f;
        __syncthreads();
        const int w0 = blk << 9;
        int cnt = gcur[blk]; if (cnt > BCAP) cnt = BCAP;
        const unsigned* base = pvB + (((size_t)blk * BCAP) << 1);
        const int i0 = tid * 8;                 // covers [0, 8192) = BCAP
        if (i0 < cnt) {
            if (i0 + 8 <= cnt) {
                const i32x4* src = (const i32x4*)(base + (i0 << 1));
                i32x4 q0 = __builtin_nontemporal_load(src);
                i32x4 q1 = __builtin_nontemporal_load(src + 1);
                i32x4 q2 = __builtin_nontemporal_load(src + 2);
                i32x4 q3 = __builtin_nontemporal_load(src + 3);
                unsigned pk[8]; float vv[8];
                pk[0] = (unsigned)q0[0]; vv[0] = __uint_as_float(q0[1]);
                pk[1] = (unsigned)q0[2]; vv[1] = __uint_as_float(q0[3]);
                pk[2] = (unsigned)q1[0]; vv[2] = __uint_as_float(q1[1]);
                pk[3] = (unsigned)q1[2]; vv[3] = __uint_as_float(q1[3]);
                pk[4] = (unsigned)q2[0]; vv[4] = __uint_as_float(q2[1]);
                pk[5] = (unsigned)q2[2]; vv[5] = __uint_as_float(q2[3]);
                pk[6] = (unsigned)q3[0]; vv[6] = __uint_as_float(q3[1]);
                pk[7] = (unsigned)q3[2]; vv[7] = __uint_as_float(q3[3]);
                float gv[8];
#pragma unroll
                for (int j = 0; j < 8; ++j)
                    gv[j] = bf2f(g[pk[j] & 0x7FFFFFu]);   // 8 gathers in flight
#pragma unroll
                for (int j = 0; j < 8; ++j)
                    atomicAdd(&win[pk[j] >> 23], -vv[j] * gv[j]);
            } else {
                for (int e2 = i0; e2 < cnt; ++e2) {
                    unsigned pk = base[e2 << 1];
                    float vv = __uint_as_float(base[(e2 << 1) + 1]);
                    atomicAdd(&win[pk >> 23], -vv * bf2f(g[pk & 0x7FFFFFu]));
                }
            }
        }
        // fold overflow entries belonging to this window (expected none)
        {
            int ocnt = ocur[0]; if (ocnt > OCAP) ocnt = OCAP;
            for (int k2 = tid; k2 < ocnt; k2 += 1024) {
                int c = ovfC[k2];
                if (c >= w0 && c < w0 + CW)
                    atomicAdd(&win[c - w0], -ovfV[k2] * bf2f(g[ovfR[k2]]));
            }
        }
        __syncthreads();
        // exclusive window ownership -> plain stores
        for (int i = tid; i < CW; i += 1024) {
            int c = w0 + i;
            if (c < 3 * N_ATOMS) F[c] = win[i];
        }
        return;
    }

    // dedicated energy blocks
    {
        const int bb = blk - CBINS;   // [0, N_IMG)
        int lo, hi;
        {
            int l = 0, r = N_ATOMS;
            while (l < r) { int m = (l + r) >> 1; if (img[m] < bb) l = m + 1; else r = m; }
            lo = l;
        }
        {
            int l = lo, r = N_ATOMS;
            while (l < r) { int m = (l + r) >> 1; if (img[m] < bb + 1) l = m + 1; else r = m; }
            hi = l;
        }
        float s = 0.f;
        for (int i2 = lo + tid; i2 < hi; i2 += 1024) s += o_atom[i2];
#pragma unroll
        for (int off = 32; off > 0; off >>= 1) s += __shfl_down(s, off, 64);
        __shared__ float red[16];
        if ((tid & 63) == 0) red[tid >> 6] = s;
        __syncthreads();
        if (tid == 0) {
            float t = 0.f;
#pragma unroll
            for (int w2 = 0; w2 < 16; ++w2) t += red[w2];
            energy[bb] = t;
        }
    }
}

// ---------------------------------------------------------------------------
extern "C" void kernel_launch(void* const* d_in, const int* in_sizes, int n_in,
                              void* d_out, int out_size, void* d_ws, size_t ws_size,
                              hipStream_t stream) {
    const float* fp    = (const float*)d_in[0];
    const int*   Z     = (const int*)d_in[1];
    const int*   img   = (const int*)d_in[2];
    const int*   frows = (const int*)d_in[3];
    const int*   fcols = (const int*)d_in[4];
    const float* fvals = (const float*)d_in[5];
    const float* W0    = (const float*)d_in[6];
    const float* b0    = (const float*)d_in[7];
    const float* W1    = (const float*)d_in[8];
    const float* b1    = (const float*)d_in[9];
    const float* W2    = (const float*)d_in[10];
    const float* b2    = (const float*)d_in[11];

    float* out    = (float*)d_out;
    float* energy = out;             // [N_IMG]
    float* F      = out + N_IMG;     // [3*N_ATOMS]

    char* ws = (char*)d_ws;
    // counts/gcur/ocur packed contiguously for one memset
    int*   counts = (int*)ws;                          // 16 B @ ws+0
    int*   gcur   = (int*)(ws + 32);                   // 1172 B @ ws+32
    int*   ocur   = (int*)(ws + 32 + 4 * CBINS);       // 4 B @ ws+1204
    int*   lists  = (int*)(ws + 4096);                 // 800 KB
    char*  base   = ws + (1 << 20);
    unsigned short* Gb   = (unsigned short*)(base);              // 12.8 MB (atom order)
    float* o_atom        = (float*)(base + 13000000);            // 200 KB
    unsigned short* W0s1 = (unsigned short*)(base + 14000000);   // 256 KB
    unsigned short* W0s4 = W0s1 + N_ELEM * IN_DIM * HID;
    unsigned short* W1s2 = W0s4 + N_ELEM * IN_DIM * HID;
    unsigned short* W1s3 = W1s2 + N_ELEM * HID * HID;
    unsigned* pvB = (unsigned*)(base + 19000000);                // 19.2 MB interleaved
    int*   ovfR  = (int*)(base + 49000000);
    int*   ovfC  = (int*)(base + 49050000);
    float* ovfV  = (float*)(base + 49100000);

    // memset(counts+gcur+ocur) -> prep||bucket -> mega(bin~mlp) -> consumer
    hipMemsetAsync(ws, 0, 32 + 4 * CBINS + 4, stream);

    prep_and_bucket<<<PREPB + BKB, 256, 0, stream>>>(
        W0, W1, W0s1, W1s2, W1s3, W0s4, Z, counts, lists, F);

    mega_mlp_bin<<<TOTB, 256, 0, stream>>>(
        fp, W0s1, W1s2, W1s3, W0s4, b0, b1, W2, b2, o_atom, Gb, counts, lists,
        frows, fcols, fvals, pvB, gcur, ovfR, ovfC, ovfV, ocur);

    forces_consumer<<<CBINS + N_IMG, 1024, 0, stream>>>(
        pvB, gcur, Gb, F, o_atom, img, energy,
        ovfR, ovfC, ovfV, ocur);
}

// Round 17
// 268.524 us; speedup vs baseline: 1.1642x; 1.1642x over previous
//
#include <hip/hip_runtime.h>
#include <math.h>

#define N_ATOMS 50000
#define IN_DIM 128
#define HID 256
#define N_ELEM 4
#define N_IMG 500
#define NNZ 2000000

// R28: R14 post-mortem — __launch_bounds__(256,5) capped unified VGPR+AGPR
// at ~102/wave -> spills (VGPR 48, +370MB scratch traffic, mega 190us).
// Fix: (256,4) restores the register budget (no spills); occupancy comes
// from LDS alone (32,768 B -> 5 blocks/CU if regs <= ~102).
#define CBINS 293        // col >> 9 over 150,016 cols
#define CW 512           // cols per bin (2 KB LDS window)
#define BCAP 8192        // expect 6826 +- 83 (16 sigma headroom)
#define OCAP 4096        // overflow list capacity (expected use: 0)
#define PCH 2304         // producer chunk (12*2304 + 4688 = 32,336 B LDS)
#define NBP ((NNZ + PCH - 1) / PCH)   // 869 producer blocks
#define TILES_PER_E 416  // 32-row tiles; covers mean+8.4sigma atoms/element
#define NFB (8 * (TILES_PER_E / 2))   // 1664 fused blocks
#define TOTB (NBP + NFB)              // 2533 mega blocks
#define BKB ((N_ATOMS + 255) / 256)   // 196 bucket blocks
#define PREPB 384                     // prep blocks

// LDS swizzle: XOR the 16B-slot bits of the short-col with row bits 2-3.
#define SWZ(row, col) ((col) ^ ((((row) >> 2) & 3) << 3))

typedef __attribute__((ext_vector_type(8))) short bf16x8;   // 8 bf16 = 4 VGPRs
typedef __attribute__((ext_vector_type(4))) float f32x4;    // MFMA C/D frag
typedef __attribute__((ext_vector_type(4))) int   i32x4;    // native vec loads
typedef __attribute__((ext_vector_type(4))) float fv4;      // native vec loads

__device__ __forceinline__ int elem_of(int z) {
    return (z == 1) ? 0 : (z == 6) ? 1 : (z == 8) ? 2 : 3;
}

__device__ __forceinline__ unsigned short f2bf(float f) {   // RNE
    unsigned u = __float_as_uint(f);
    u += 0x7fffu + ((u >> 16) & 1u);
    return (unsigned short)(u >> 16);
}
__device__ __forceinline__ float bf2f(unsigned short u) {
    return __uint_as_float(((unsigned)u) << 16);
}
__device__ __forceinline__ float tanh_fast(float x) {
    float e = __expf(2.f * x);
    return (e - 1.f) / (e + 1.f);
}

// ---------------------------------------------------------------------------
// K1) prep_weights + bucket_atoms in one dispatch (R22). Unchanged.
// ---------------------------------------------------------------------------
__global__ __launch_bounds__(256) void prep_and_bucket(
    const float* __restrict__ W0, const float* __restrict__ W1,
    unsigned short* __restrict__ W0s1,   // stage1: Bt[h][d], K=128, KN=4
    unsigned short* __restrict__ W1s2,   // stage2: Bt[h1][h0], K=256, KN=8
    unsigned short* __restrict__ W1s3,   // stage3: Bt[h0][h1], K=256, KN=8
    unsigned short* __restrict__ W0s4,   // stage4: Bt[d][h], K=256, KN=8
    const int* __restrict__ Z, int* __restrict__ counts,
    int* __restrict__ lists, float* __restrict__ F) {

    const int tid = threadIdx.x;

    if (blockIdx.x >= PREPB) {
        // ----- atom bucketing + F zeroing -----
        __shared__ int lcnt[N_ELEM], lbase[N_ELEM];
        const int bb = blockIdx.x - PREPB;
        for (int idx = bb * 256 + tid; idx < 3 * N_ATOMS; idx += BKB * 256)
            F[idx] = 0.f;
        const int i = bb * 256 + tid;
        if (tid < N_ELEM) lcnt[tid] = 0;
        __syncthreads();
        int e = -1, pos = 0;
        if (i < N_ATOMS) {
            e = elem_of(Z[i]);
            pos = atomicAdd(&lcnt[e], 1);
        }
        __syncthreads();
        if (tid < N_ELEM) lbase[tid] = atomicAdd(&counts[tid], lcnt[tid]);
        __syncthreads();
        if (i < N_ATOMS) lists[e * N_ATOMS + lbase[e] + pos] = i;
        return;
    }

    const int T = blockIdx.x * 256 + tid;   // [0, 98304)

    if (T < 32768) {
        // W1s2: row=n(h1), col=k(h0). frag spans k&7; k-gather stride 256.
        const int e = T >> 13, fid = T & 8191;
        const int blkv = fid >> 6, lane = fid & 63;
        const int k0 = ((blkv & 7) << 5) | ((lane >> 4) << 3);
        const int n  = ((blkv >> 3) << 4) | (lane & 15);
        const float* src = W1 + e * 65536 + n;
        bf16x8 vv;
#pragma unroll
        for (int j = 0; j < 8; ++j) vv[j] = (short)f2bf(src[(k0 + j) * 256]);
        *(bf16x8*)(W1s2 + (e << 16) + (fid << 3)) = vv;
    } else if (T < 65536) {
        // W1s3: row=k(h0), col=n(h1). frag spans n&7 -> 8 contiguous floats.
        const int u = T - 32768, e = u >> 13, fid = u & 8191;
        const int blkv = fid >> 6, lane = fid & 63;
        const int k  = ((blkv >> 3) << 4) | (lane & 15);
        const int n0 = ((blkv & 7) << 5) | ((lane >> 4) << 3);
        const float* src = W1 + e * 65536 + k * 256 + n0;
        float4 a = *(const float4*)src;
        float4 b = *(const float4*)(src + 4);
        bf16x8 vv;
        vv[0] = (short)f2bf(a.x); vv[1] = (short)f2bf(a.y);
        vv[2] = (short)f2bf(a.z); vv[3] = (short)f2bf(a.w);
        vv[4] = (short)f2bf(b.x); vv[5] = (short)f2bf(b.y);
        vv[6] = (short)f2bf(b.z); vv[7] = (short)f2bf(b.w);
        *(bf16x8*)(W1s3 + (e << 16) + (fid << 3)) = vv;
    } else if (T < 81920) {
        // W0s1: row=n(h), col=k(d), K=128. frag spans k&7; k-gather.
        const int u = T - 65536, e = u >> 12, fid = u & 4095;
        const int blkv = fid >> 6, lane = fid & 63;
        const int k0 = ((blkv & 3) << 5) | ((lane >> 4) << 3);
        const int n  = ((blkv >> 2) << 4) | (lane & 15);
        const float* src = W0 + e * 32768 + n;
        bf16x8 vv;
#pragma unroll
        for (int j = 0; j < 8; ++j) vv[j] = (short)f2bf(src[(k0 + j) * 256]);
        *(bf16x8*)(W0s1 + e * 32768 + (fid << 3)) = vv;
    } else if (T < 98304) {
        // W0s4: row=k(d), col=n(h). frag spans n&7 -> 8 contiguous floats.
        const int u = T - 81920, e = u >> 12, fid = u & 4095;
        const int blkv = fid >> 6, lane = fid & 63;
        const int k  = ((blkv >> 3) << 4) | (lane & 15);
        const int n0 = ((blkv & 7) << 5) | ((lane >> 4) << 3);
        const float* src = W0 + e * 32768 + k * 256 + n0;
        float4 a = *(const float4*)src;
        float4 b = *(const float4*)(src + 4);
        bf16x8 vv;
        vv[0] = (short)f2bf(a.x); vv[1] = (short)f2bf(a.y);
        vv[2] = (short)f2bf(a.z); vv[3] = (short)f2bf(a.w);
        vv[4] = (short)f2bf(b.x); vv[5] = (short)f2bf(b.y);
        vv[6] = (short)f2bf(b.z); vv[7] = (short)f2bf(b.w);
        *(bf16x8*)(W0s4 + e * 32768 + (fid << 3)) = vv;
    }
}

// ---------------------------------------------------------------------------
// K2) MEGA dispatch — R28: launch_bounds (256,4) [R14's (256,5) spilled];
//     LDS 32,768 B so HW can reach 5 blocks/CU if regs permit. Swizzled
//     stride-32 tiles, Bresenham interleave, uint2 scatter, wave-scan.
// ---------------------------------------------------------------------------
#define CH 1024           // chunk stride in shorts (32*32, swizzled)
__global__ __launch_bounds__(256, 4) void mega_mlp_bin(
    // fused args
    const float* __restrict__ fp,
    const unsigned short* __restrict__ W0s1,
    const unsigned short* __restrict__ W1s2,
    const unsigned short* __restrict__ W1s3,
    const unsigned short* __restrict__ W0s4,
    const float* __restrict__ b0, const float* __restrict__ b1,
    const float* __restrict__ W2, const float* __restrict__ b2,
    float* __restrict__ o_atom,
    unsigned short* __restrict__ Gb,
    const int* __restrict__ counts, const int* __restrict__ lists,
    // producer args
    const int* __restrict__ rows, const int* __restrict__ cols,
    const float* __restrict__ vals,
    unsigned* __restrict__ pvB,
    int* __restrict__ gcur,
    int* __restrict__ ovfR, int* __restrict__ ovfC, float* __restrict__ ovfV,
    int* __restrict__ ocur) {

    __shared__ __align__(16) char smem[32768];
    const int tid = threadIdx.x;

    // Bresenham split: producers spread evenly through dispatch order.
    const int bid = blockIdx.x;
    const int pA = (bid * NBP) / TOTB;          // producers before bid
    const int pB = ((bid + 1) * NBP) / TOTB;    // producers before bid+1

    if (pB > pA) {
        // =================== COO bin producer (pidx = pA) ===================
        int*   Lr    = (int*)smem;                    // 2304*4 = 9216 B
        int*   Lc    = (int*)(smem + 9216);           // 9216 B
        float* Lv    = (float*)(smem + 18432);        // 9216 B
        int*   hist  = (int*)(smem + 27648);          // 1172 B
        int*   pref  = (int*)(smem + 28820);
        int*   curs  = (int*)(smem + 29992);
        int*   gbase = (int*)(smem + 31164);          // ends at 32336

        const int base = pA * PCH;
        const int lim = (base + PCH <= NNZ) ? PCH : (NNZ - base);

        for (int i = tid; i < CBINS; i += 256) hist[i] = 0;
        __syncthreads();

        // phase 1: stash 2304 entries (3 x int4 groups) + LDS histogram
        i32x4 r[3], c[3];
        fv4   v[3];
        int nvalid[3];
#pragma unroll
        for (int j = 0; j < 3; ++j) {
            const int li = tid * 4 + 1024 * j;
            const int i0 = base + li;
            int nv = lim - li;
            nvalid[j] = nv > 4 ? 4 : (nv < 0 ? 0 : nv);
            if (nvalid[j] == 4) {
                r[j] = __builtin_nontemporal_load((const i32x4*)(rows + i0));
                c[j] = __builtin_nontemporal_load((const i32x4*)(cols + i0));
                v[j] = __builtin_nontemporal_load((const fv4*)(vals + i0));
            } else {
                for (int e2 = 0; e2 < nvalid[j]; ++e2) {
                    r[j][e2] = rows[i0 + e2]; c[j][e2] = cols[i0 + e2];
                    v[j][e2] = vals[i0 + e2];
                }
            }
#pragma unroll
            for (int e2 = 0; e2 < 4; ++e2)
                if (e2 < nvalid[j]) atomicAdd(&hist[c[j][e2] >> 9], 1);
        }
        __syncthreads();

        // phase 2: wave-parallel exclusive prefix over 293 bins
        if (tid < 64) {
            int carry = 0;
#pragma unroll
            for (int cch = 0; cch < 5; ++cch) {
                const int i = cch * 64 + tid;
                const int h = (i < CBINS) ? hist[i] : 0;
                int x = h;
#pragma unroll
                for (int off = 1; off < 64; off <<= 1) {
                    int y = __shfl_up(x, off, 64);
                    if (tid >= off) x += y;
                }
                if (i < CBINS) pref[i] = carry + x - h;   // exclusive
                carry += __shfl(x, 63, 64);
            }
        }
        __syncthreads();
        // phase 2.5: reserve global ranges; init cursors
        for (int b = tid; b < CBINS; b += 256) {
            gbase[b] = atomicAdd(&gcur[b], hist[b]);
            curs[b] = pref[b];
        }
        __syncthreads();

        // phase 3: scatter into LDS (counting-sort order)
#pragma unroll
        for (int j = 0; j < 3; ++j)
#pragma unroll
            for (int e2 = 0; e2 < 4; ++e2)
                if (e2 < nvalid[j]) {
                    int b = c[j][e2] >> 9;
                    int p = atomicAdd(&curs[b], 1);
                    Lr[p] = r[j][e2]; Lc[p] = c[j][e2]; Lv[p] = v[j][e2];
                }
        __syncthreads();

        // phase 4: linear LDS -> global, ONE uint2 {pack,val} per entry
#pragma unroll
        for (int j = 0; j < 9; ++j) {
            const int p = tid + 256 * j;
            if (p >= lim) break;
            const int col = Lc[p];
            const int b = col >> 9;
            const int g = gbase[b] + (p - pref[b]);
            if (g < BCAP) {
                uint2 w;
                w.x = ((unsigned)(col & 511) << 23) | (unsigned)Lr[p];
                w.y = __float_as_uint(Lv[p]);
                *(uint2*)(pvB + (((size_t)b * BCAP + g) << 1)) = w;
            } else {
                int od = atomicAdd(ocur, 1);
                if (od < OCAP) { ovfR[od] = Lr[p]; ovfC[od] = col; ovfV[od] = Lv[p]; }
            }
        }
        return;
    }

    // =================== fused MLP fwd+bwd (swizzled stride-32) ============
    const int fid = bid - pB;
    const int xcd = fid & 7;
    const int e = xcd & 3;
    const int tile = (fid >> 3) * 2 + (xcd >> 2);
    const int cnt = counts[e];
    const int m0 = tile * 32;
    if (m0 >= cnt) return;
    const int* list = lists + e * N_ATOMS;

    short* tH = (short*)smem;                    // 16384 B
    short* tD = (short*)(smem + 16384);          // 16384 B (chunk4: energy red)

    const int lane = tid & 63;
    const int wv = tid >> 6;       // 0..3, n-range wv*64
    const int lr = lane & 15;
    const int lq = lane >> 4;
    const int fsw = ((lr >> 2) & 3) << 3;   // frag-read swizzle (row==lr mod 16)

    const unsigned short* B1 = W0s1 + (size_t)e * HID * IN_DIM;
    const unsigned short* B2 = W1s2 + (size_t)e * HID * HID;
    const unsigned short* B3 = W1s3 + (size_t)e * HID * HID;
    const unsigned short* B4 = W0s4 + (size_t)e * IN_DIM * HID;

    f32x4 acc[2][4];
    float osumR[2][4];             // energy partials, e2 -> e4 (lanes lr==0)
#define ZERO_ACC()                                                        \
    _Pragma("unroll") for (int mt = 0; mt < 2; ++mt)                      \
        _Pragma("unroll") for (int nt = 0; nt < 4; ++nt)                  \
            _Pragma("unroll") for (int j = 0; j < 4; ++j) acc[mt][nt][j] = 0.f;

    // ---- S1 A-tile staging ----
    {
        bf16x8 bb0[4];   // hoisted B ki=0 preload (flies during staging)
#pragma unroll
        for (int nt = 0; nt < 4; ++nt)
            bb0[nt] = *(const bf16x8*)(B1 +
                ((size_t)(((wv * 4 + nt) * 4 + 0) * 64 + lane) << 3));

#pragma unroll
        for (int p = 0; p < 4; ++p) {
            const int row = p * 8 + (tid >> 5);
            const int col = (tid & 31) * 4;          // float index in row
            const int m = m0 + row;
            float4 a = make_float4(0.f, 0.f, 0.f, 0.f);
            if (m < cnt)
                a = *(const float4*)(fp + (size_t)list[m] * IN_DIM + col);
            short4 b;
            b.x = (short)f2bf(a.x); b.y = (short)f2bf(a.y);
            b.z = (short)f2bf(a.z); b.w = (short)f2bf(a.w);
            *(short4*)&tD[(col >> 5) * CH + row * 32 + SWZ(row, col & 31)] = b;
        }
        __syncthreads();

        // =============== Stage 1: z0 = A @ W0^T  (K=128, KN=4, B ring-2) ===
        ZERO_ACC();
        bf16x8 bb[2][4];
#pragma unroll
        for (int nt = 0; nt < 4; ++nt) bb[0][nt] = bb0[nt];
#pragma unroll
        for (int ki = 0; ki < 4; ++ki) {
            const int cur = ki & 1, nx = cur ^ 1;
            if (ki < 3) {
#pragma unroll
                for (int nt = 0; nt < 4; ++nt)
                    bb[nx][nt] = *(const bf16x8*)(B1 +
                        ((size_t)(((wv * 4 + nt) * 4 + ki + 1) * 64 + lane) << 3));
            }
            bf16x8 af[2];
#pragma unroll
            for (int mt = 0; mt < 2; ++mt)
                af[mt] = *(const bf16x8*)&tD[ki * CH + (mt * 16 + lr) * 32 + (lq * 8 ^ fsw)];
#pragma unroll
            for (int mt = 0; mt < 2; ++mt)
#pragma unroll
                for (int nt = 0; nt < 4; ++nt)
                    acc[mt][nt] = __builtin_amdgcn_mfma_f32_16x16x32_bf16(
                        af[mt], bb[cur][nt], acc[mt][nt], 0, 0, 0);
        }
    }

    // S2 B-ring preload
    bf16x8 b2r[3][4];
#pragma unroll
    for (int p = 0; p < 3; ++p)
#pragma unroll
        for (int nt = 0; nt < 4; ++nt)
            b2r[p][nt] = *(const bf16x8*)(B2 +
                ((size_t)(((wv * 4 + nt) * 8 + p) * 64 + lane) << 3));

    // epilogue 1: h0 -> tH
    {
        float bv[4];
#pragma unroll
        for (int nt = 0; nt < 4; ++nt)
            bv[nt] = b0[e * HID + wv * 64 + nt * 16 + lr];
#pragma unroll
        for (int mt = 0; mt < 2; ++mt)
#pragma unroll
            for (int rr = 0; rr < 4; ++rr) {
                const int row = mt * 16 + lq * 4 + rr;
#pragma unroll
                for (int nt = 0; nt < 4; ++nt) {
                    const int n = wv * 64 + nt * 16 + lr;
                    float t = tanh_fast(acc[mt][nt][rr] + bv[nt]);
                    tH[(n >> 5) * CH + row * 32 + SWZ(row, n & 31)] = (short)f2bf(t);
                }
            }
    }
    __syncthreads();

    // =============== Stage 2: z1 = h0 @ W1^T   (K=256, ring-3) =============
    ZERO_ACC();
#pragma unroll
    for (int ki = 0; ki < 8; ++ki) {
        bf16x8 af[2];
#pragma unroll
        for (int mt = 0; mt < 2; ++mt)
            af[mt] = *(const bf16x8*)&tH[ki * CH + (mt * 16 + lr) * 32 + (lq * 8 ^ fsw)];
#pragma unroll
        for (int mt = 0; mt < 2; ++mt)
#pragma unroll
            for (int nt = 0; nt < 4; ++nt)
                acc[mt][nt] = __builtin_amdgcn_mfma_f32_16x16x32_bf16(
                    af[mt], b2r[ki % 3][nt], acc[mt][nt], 0, 0, 0);
        if (ki < 5) {
#pragma unroll
            for (int nt = 0; nt < 4; ++nt)
                b2r[ki % 3][nt] = *(const bf16x8*)(B2 +
                    ((size_t)(((wv * 4 + nt) * 8 + ki + 3) * 64 + lane) << 3));
        }
    }

    // S3 B-ring preload
    bf16x8 b3r[3][4];
#pragma unroll
    for (int p = 0; p < 3; ++p)
#pragma unroll
        for (int nt = 0; nt < 4; ++nt)
            b3r[p][nt] = *(const bf16x8*)(B3 +
                ((size_t)(((wv * 4 + nt) * 8 + p) * 64 + lane) << 3));

    // epilogue 2: dz1 -> tD; o partials -> osumR regs (written to LDS in e4)
    {
        float bv[4], w2v[4];
#pragma unroll
        for (int nt = 0; nt < 4; ++nt) {
            bv[nt]  = b1[e * HID + wv * 64 + nt * 16 + lr];
            w2v[nt] = W2[e * HID + wv * 64 + nt * 16 + lr];
        }
#pragma unroll
        for (int mt = 0; mt < 2; ++mt)
#pragma unroll
            for (int rr = 0; rr < 4; ++rr) {
                const int row = mt * 16 + lq * 4 + rr;
                float osum = 0.f;
#pragma unroll
                for (int nt = 0; nt < 4; ++nt) {
                    const int n = wv * 64 + nt * 16 + lr;
                    float t = tanh_fast(acc[mt][nt][rr] + bv[nt]);
                    osum += t * w2v[nt];
                    tD[(n >> 5) * CH + row * 32 + SWZ(row, n & 31)] =
                        (short)f2bf(w2v[nt] * (1.f - t * t));
                }
                osum += __shfl_xor(osum, 1, 64);
                osum += __shfl_xor(osum, 2, 64);
                osum += __shfl_xor(osum, 4, 64);
                osum += __shfl_xor(osum, 8, 64);
                osumR[mt][rr] = osum;          // valid on all lanes of group
            }
    }
    __syncthreads();

    // =============== Stage 3: dh0 = dz1 @ W1   (K=256, ring-3) =============
    ZERO_ACC();
#pragma unroll
    for (int ki = 0; ki < 8; ++ki) {
        bf16x8 af[2];
#pragma unroll
        for (int mt = 0; mt < 2; ++mt)
            af[mt] = *(const bf16x8*)&tD[ki * CH + (mt * 16 + lr) * 32 + (lq * 8 ^ fsw)];
#pragma unroll
        for (int mt = 0; mt < 2; ++mt)
#pragma unroll
            for (int nt = 0; nt < 4; ++nt)
                acc[mt][nt] = __builtin_amdgcn_mfma_f32_16x16x32_bf16(
                    af[mt], b3r[ki % 3][nt], acc[mt][nt], 0, 0, 0);
        if (ki < 5) {
#pragma unroll
            for (int nt = 0; nt < 4; ++nt)
                b3r[ki % 3][nt] = *(const bf16x8*)(B3 +
                    ((size_t)(((wv * 4 + nt) * 8 + ki + 3) * 64 + lane) << 3));
        }
    }

    // S4 B-ring preload
    bf16x8 b4r[3][2];
#pragma unroll
    for (int p = 0; p < 3; ++p)
#pragma unroll
        for (int nt = 0; nt < 2; ++nt)
            b4r[p][nt] = *(const bf16x8*)(B4 +
                ((size_t)(((wv * 2 + nt) * 8 + p) * 64 + lane) << 3));

    // epilogue 3: dz0 = dh0*(1-h0^2) -> tH in-place (same thread owns slot)
#pragma unroll
    for (int mt = 0; mt < 2; ++mt)
#pragma unroll
        for (int rr = 0; rr < 4; ++rr) {
            const int row = mt * 16 + lq * 4 + rr;
#pragma unroll
            for (int nt = 0; nt < 4; ++nt) {
                const int n = wv * 64 + nt * 16 + lr;
                const int a = (n >> 5) * CH + row * 32 + SWZ(row, n & 31);
                float h = bf2f((unsigned short)tH[a]);
                tH[a] = (short)f2bf(acc[mt][nt][rr] * (1.f - h * h));
            }
        }
    __syncthreads();

    // =============== Stage 4: g = dz0 @ W0   (K=256, NT=2, ring-3) =========
    {
        f32x4 a4[2][2];
#pragma unroll
        for (int mt = 0; mt < 2; ++mt)
#pragma unroll
            for (int nt = 0; nt < 2; ++nt)
#pragma unroll
                for (int j = 0; j < 4; ++j) a4[mt][nt][j] = 0.f;
#pragma unroll
        for (int ki = 0; ki < 8; ++ki) {
            bf16x8 af[2];
#pragma unroll
            for (int mt = 0; mt < 2; ++mt)
                af[mt] = *(const bf16x8*)&tH[ki * CH + (mt * 16 + lr) * 32 + (lq * 8 ^ fsw)];
#pragma unroll
            for (int mt = 0; mt < 2; ++mt)
#pragma unroll
                for (int nt = 0; nt < 2; ++nt)
                    a4[mt][nt] = __builtin_amdgcn_mfma_f32_16x16x32_bf16(
                        af[mt], b4r[ki % 3][nt], a4[mt][nt], 0, 0, 0);
            if (ki < 5) {
#pragma unroll
                for (int nt = 0; nt < 2; ++nt)
                    b4r[ki % 3][nt] = *(const bf16x8*)(B4 +
                        ((size_t)(((wv * 2 + nt) * 8 + ki + 3) * 64 + lane) << 3));
            }
        }
        // epilogue 4: g -> tD chunks 0..3; energy partials -> tD chunk 4
        //   (chunks 4..7 dead: last read in S3, barrier after e3 passed)
#pragma unroll
        for (int mt = 0; mt < 2; ++mt)
#pragma unroll
            for (int rr = 0; rr < 4; ++rr) {
                const int row = mt * 16 + lq * 4 + rr;
#pragma unroll
                for (int nt = 0; nt < 2; ++nt) {
                    const int n = wv * 32 + nt * 16 + lr;
                    tD[(n >> 5) * CH + row * 32 + SWZ(row, n & 31)] =
                        (short)f2bf(a4[mt][nt][rr]);
                }
                if (lr == 0)
                    ((float*)&tD[4 * CH])[wv * 32 + row] = osumR[mt][rr];
            }
    }
    __syncthreads();
#pragma unroll
    for (int t = 0; t < 2; ++t) {
        const int c = tid + 256 * t;         // 0..511
        const int row = c >> 4;              // 0..31
        const int pos = (c & 15) * 8;        // 0..120
        const int m = m0 + row;
        if (m < cnt) {
            bf16x8 v = *(const bf16x8*)&tD[(pos >> 5) * CH + row * 32 + SWZ(row, pos & 31)];
            *(bf16x8*)(Gb + (size_t)list[m] * IN_DIM + pos) = v;
        }
    }
    if (tid < 32) {
        int m = m0 + tid;
        if (m < cnt) {
            const float* rp = (const float*)&tD[4 * CH];
            o_atom[list[m]] = rp[tid] + rp[32 + tid] + rp[64 + tid] +
                              rp[96 + tid] + b2[e];
        }
    }
#undef ZERO_ACC
}

// ---------------------------------------------------------------------------
// K3) Forces consumer — unchanged from R25: one block per col-window,
//     unroll-8 single pass, NT pvB loads, plain F stores.
// ---------------------------------------------------------------------------
__global__ __launch_bounds__(1024) void forces_consumer(
    const unsigned* __restrict__ pvB,
    const int* __restrict__ gcur,
    const unsigned short* __restrict__ g, float* __restrict__ F,
    const float* __restrict__ o_atom, const int* __restrict__ img,
    float* __restrict__ energy,
    const int* __restrict__ ovfR, const int* __restrict__ ovfC,
    const float* __restrict__ ovfV, const int* __restrict__ ocur) {

    const int blk = blockIdx.x;
    const int tid = threadIdx.x;

    if (blk < CBINS) {
        __shared__ float win[CW];
        for (int i = tid; i < CW; i += 1024) win[i] = 0.f;
        __syncthreads();
        const int w0 = blk << 9;
        int cnt = gcur[blk]; if (cnt > BCAP) cnt = BCAP;
        const unsigned* base = pvB + (((size_t)blk * BCAP) << 1);
        const int i0 = tid * 8;                 // covers [0, 8192) = BCAP
        if (i0 < cnt) {
            if (i0 + 8 <= cnt) {
                const i32x4* src = (const i32x4*)(base + (i0 << 1));
                i32x4 q0 = __builtin_nontemporal_load(src);
                i32x4 q1 = __builtin_nontemporal_load(src + 1);
                i32x4 q2 = __builtin_nontemporal_load(src + 2);
                i32x4 q3 = __builtin_nontemporal_load(src + 3);
                unsigned pk[8]; float vv[8];
                pk[0] = (unsigned)q0[0]; vv[0] = __uint_as_float(q0[1]);
                pk[1] = (unsigned)q0[2]; vv[1] = __uint_as_float(q0[3]);
                pk[2] = (unsigned)q1[0]; vv[2] = __uint_as_float(q1[1]);
                pk[3] = (unsigned)q1[2]; vv[3] = __uint_as_float(q1[3]);
                pk[4] = (unsigned)q2[0]; vv[4] = __uint_as_float(q2[1]);
                pk[5] = (unsigned)q2[2]; vv[5] = __uint_as_float(q2[3]);
                pk[6] = (unsigned)q3[0]; vv[6] = __uint_as_float(q3[1]);
                pk[7] = (unsigned)q3[2]; vv[7] = __uint_as_float(q3[3]);
                float gv[8];
#pragma unroll
                for (int j = 0; j < 8; ++j)
                    gv[j] = bf2f(g[pk[j] & 0x7FFFFFu]);   // 8 gathers in flight
#pragma unroll
                for (int j = 0; j < 8; ++j)
                    atomicAdd(&win[pk[j] >> 23], -vv[j] * gv[j]);
            } else {
                for (int e2 = i0; e2 < cnt; ++e2) {
                    unsigned pk = base[e2 << 1];
                    float vv = __uint_as_float(base[(e2 << 1) + 1]);
                    atomicAdd(&win[pk >> 23], -vv * bf2f(g[pk & 0x7FFFFFu]));
                }
            }
        }
        // fold overflow entries belonging to this window (expected none)
        {
            int ocnt = ocur[0]; if (ocnt > OCAP) ocnt = OCAP;
            for (int k2 = tid; k2 < ocnt; k2 += 1024) {
                int c = ovfC[k2];
                if (c >= w0 && c < w0 + CW)
                    atomicAdd(&win[c - w0], -ovfV[k2] * bf2f(g[ovfR[k2]]));
            }
        }
        __syncthreads();
        // exclusive window ownership -> plain stores
        for (int i = tid; i < CW; i += 1024) {
            int c = w0 + i;
            if (c < 3 * N_ATOMS) F[c] = win[i];
        }
        return;
    }

    // dedicated energy blocks
    {
        const int bb = blk - CBINS;   // [0, N_IMG)
        int lo, hi;
        {
            int l = 0, r = N_ATOMS;
            while (l < r) { int m = (l + r) >> 1; if (img[m] < bb) l = m + 1; else r = m; }
            lo = l;
        }
        {
            int l = lo, r = N_ATOMS;
            while (l < r) { int m = (l + r) >> 1; if (img[m] < bb + 1) l = m + 1; else r = m; }
            hi = l;
        }
        float s = 0.f;
        for (int i2 = lo + tid; i2 < hi; i2 += 1024) s += o_atom[i2];
#pragma unroll
        for (int off = 32; off > 0; off >>= 1) s += __shfl_down(s, off, 64);
        __shared__ float red[16];
        if ((tid & 63) == 0) red[tid >> 6] = s;
        __syncthreads();
        if (tid == 0) {
            float t = 0.f;
#pragma unroll
            for (int w2 = 0; w2 < 16; ++w2) t += red[w2];
            energy[bb] = t;
        }
    }
}

// ---------------------------------------------------------------------------
extern "C" void kernel_launch(void* const* d_in, const int* in_sizes, int n_in,
                              void* d_out, int out_size, void* d_ws, size_t ws_size,
                              hipStream_t stream) {
    const float* fp    = (const float*)d_in[0];
    const int*   Z     = (const int*)d_in[1];
    const int*   img   = (const int*)d_in[2];
    const int*   frows = (const int*)d_in[3];
    const int*   fcols = (const int*)d_in[4];
    const float* fvals = (const float*)d_in[5];
    const float* W0    = (const float*)d_in[6];
    const float* b0    = (const float*)d_in[7];
    const float* W1    = (const float*)d_in[8];
    const float* b1    = (const float*)d_in[9];
    const float* W2    = (const float*)d_in[10];
    const float* b2    = (const float*)d_in[11];

    float* out    = (float*)d_out;
    float* energy = out;             // [N_IMG]
    float* F      = out + N_IMG;     // [3*N_ATOMS]

    char* ws = (char*)d_ws;
    // counts/gcur/ocur packed contiguously for one memset
    int*   counts = (int*)ws;                          // 16 B @ ws+0
    int*   gcur   = (int*)(ws + 32);                   // 1172 B @ ws+32
    int*   ocur   = (int*)(ws + 32 + 4 * CBINS);       // 4 B @ ws+1204
    int*   lists  = (int*)(ws + 4096);                 // 800 KB
    char*  base   = ws + (1 << 20);
    unsigned short* Gb   = (unsigned short*)(base);              // 12.8 MB (atom order)
    float* o_atom        = (float*)(base + 13000000);            // 200 KB
    unsigned short* W0s1 = (unsigned short*)(base + 14000000);   // 256 KB
    unsigned short* W0s4 = W0s1 + N_ELEM * IN_DIM * HID;
    unsigned short* W1s2 = W0s4 + N_ELEM * IN_DIM * HID;
    unsigned short* W1s3 = W1s2 + N_ELEM * HID * HID;
    unsigned* pvB = (unsigned*)(base + 19000000);                // 19.2 MB interleaved
    int*   ovfR  = (int*)(base + 49000000);
    int*   ovfC  = (int*)(base + 49050000);
    float* ovfV  = (float*)(base + 49100000);

    // memset(counts+gcur+ocur) -> prep||bucket -> mega(bin~mlp) -> consumer
    hipMemsetAsync(ws, 0, 32 + 4 * CBINS + 4, stream);

    prep_and_bucket<<<PREPB + BKB, 256, 0, stream>>>(
        W0, W1, W0s1, W1s2, W1s3, W0s4, Z, counts, lists, F);

    mega_mlp_bin<<<TOTB, 256, 0, stream>>>(
        fp, W0s1, W1s2, W1s3, W0s4, b0, b1, W2, b2, o_atom, Gb, counts, lists,
        frows, fcols, fvals, pvB, gcur, ovfR, ovfC, ovfV, ocur);

    forces_consumer<<<CBINS + N_IMG, 1024, 0, stream>>>(
        pvB, gcur, Gb, F, o_atom, img, energy,
        ovfR, ovfC, ovfV, ocur);
}

// Round 18
// 193.848 us; speedup vs baseline: 1.6127x; 1.3852x over previous
//
#include <hip/hip_runtime.h>
#include <math.h>

#define N_ATOMS 50000
#define IN_DIM 128
#define HID 256
#define N_ELEM 4
#define N_IMG 500
#define NNZ 2000000

// R30: REVERT to the measured-best R12 config (194.0 us): stride-40 tiles,
// LDS 40,960 B (4 blocks/CU, no spills), uint2 pvB, wave-scan prefix,
// PCH 3008, TILES_PER_E 416, R25 consumer. R14/R17 proved 5 blocks/CU is
// unreachable (spills/scratch: +200MB traffic) and stride-32 swizzle has
// worse bank conflicts (4.1M vs 2.3M). This is the stable optimum.
#define CBINS 293        // col >> 9 over 150,016 cols
#define CW 512           // cols per bin (2 KB LDS window)
#define BCAP 8192        // expect 6826 +- 83 (16 sigma headroom)
#define OCAP 4096        // overflow list capacity (expected use: 0)
#define PCH 3008         // producer chunk (12*3008 + 4688 = 40,784 B LDS)
#define NBP ((NNZ + PCH - 1) / PCH)   // 665 producer blocks
#define TILES_PER_E 416  // 32-row tiles; covers mean+8.4sigma atoms/element
#define NFB (8 * (TILES_PER_E / 2))   // 1664 fused blocks
#define TOTB (NBP + NFB)              // 2329 mega blocks
#define BKB ((N_ATOMS + 255) / 256)   // 196 bucket blocks
#define PREPB 384                     // prep blocks

typedef __attribute__((ext_vector_type(8))) short bf16x8;   // 8 bf16 = 4 VGPRs
typedef __attribute__((ext_vector_type(4))) float f32x4;    // MFMA C/D frag
typedef __attribute__((ext_vector_type(4))) int   i32x4;    // native vec loads
typedef __attribute__((ext_vector_type(4))) float fv4;      // native vec loads

__device__ __forceinline__ int elem_of(int z) {
    return (z == 1) ? 0 : (z == 6) ? 1 : (z == 8) ? 2 : 3;
}

__device__ __forceinline__ unsigned short f2bf(float f) {   // RNE
    unsigned u = __float_as_uint(f);
    u += 0x7fffu + ((u >> 16) & 1u);
    return (unsigned short)(u >> 16);
}
__device__ __forceinline__ float bf2f(unsigned short u) {
    return __uint_as_float(((unsigned)u) << 16);
}
__device__ __forceinline__ float tanh_fast(float x) {
    float e = __expf(2.f * x);
    return (e - 1.f) / (e + 1.f);
}

// ---------------------------------------------------------------------------
// K1) prep_weights + bucket_atoms in one dispatch (R22).
// ---------------------------------------------------------------------------
__global__ __launch_bounds__(256) void prep_and_bucket(
    const float* __restrict__ W0, const float* __restrict__ W1,
    unsigned short* __restrict__ W0s1,   // stage1: Bt[h][d], K=128, KN=4
    unsigned short* __restrict__ W1s2,   // stage2: Bt[h1][h0], K=256, KN=8
    unsigned short* __restrict__ W1s3,   // stage3: Bt[h0][h1], K=256, KN=8
    unsigned short* __restrict__ W0s4,   // stage4: Bt[d][h], K=256, KN=8
    const int* __restrict__ Z, int* __restrict__ counts,
    int* __restrict__ lists, float* __restrict__ F) {

    const int tid = threadIdx.x;

    if (blockIdx.x >= PREPB) {
        // ----- atom bucketing + F zeroing -----
        __shared__ int lcnt[N_ELEM], lbase[N_ELEM];
        const int bb = blockIdx.x - PREPB;
        for (int idx = bb * 256 + tid; idx < 3 * N_ATOMS; idx += BKB * 256)
            F[idx] = 0.f;
        const int i = bb * 256 + tid;
        if (tid < N_ELEM) lcnt[tid] = 0;
        __syncthreads();
        int e = -1, pos = 0;
        if (i < N_ATOMS) {
            e = elem_of(Z[i]);
            pos = atomicAdd(&lcnt[e], 1);
        }
        __syncthreads();
        if (tid < N_ELEM) lbase[tid] = atomicAdd(&counts[tid], lcnt[tid]);
        __syncthreads();
        if (i < N_ATOMS) lists[e * N_ATOMS + lbase[e] + pos] = i;
        return;
    }

    const int T = blockIdx.x * 256 + tid;   // [0, 98304)

    if (T < 32768) {
        // W1s2: row=n(h1), col=k(h0). frag spans k&7; k-gather stride 256.
        const int e = T >> 13, fid = T & 8191;
        const int blkv = fid >> 6, lane = fid & 63;
        const int k0 = ((blkv & 7) << 5) | ((lane >> 4) << 3);
        const int n  = ((blkv >> 3) << 4) | (lane & 15);
        const float* src = W1 + e * 65536 + n;
        bf16x8 vv;
#pragma unroll
        for (int j = 0; j < 8; ++j) vv[j] = (short)f2bf(src[(k0 + j) * 256]);
        *(bf16x8*)(W1s2 + (e << 16) + (fid << 3)) = vv;
    } else if (T < 65536) {
        // W1s3: row=k(h0), col=n(h1). frag spans n&7 -> 8 contiguous floats.
        const int u = T - 32768, e = u >> 13, fid = u & 8191;
        const int blkv = fid >> 6, lane = fid & 63;
        const int k  = ((blkv >> 3) << 4) | (lane & 15);
        const int n0 = ((blkv & 7) << 5) | ((lane >> 4) << 3);
        const float* src = W1 + e * 65536 + k * 256 + n0;
        float4 a = *(const float4*)src;
        float4 b = *(const float4*)(src + 4);
        bf16x8 vv;
        vv[0] = (short)f2bf(a.x); vv[1] = (short)f2bf(a.y);
        vv[2] = (short)f2bf(a.z); vv[3] = (short)f2bf(a.w);
        vv[4] = (short)f2bf(b.x); vv[5] = (short)f2bf(b.y);
        vv[6] = (short)f2bf(b.z); vv[7] = (short)f2bf(b.w);
        *(bf16x8*)(W1s3 + (e << 16) + (fid << 3)) = vv;
    } else if (T < 81920) {
        // W0s1: row=n(h), col=k(d), K=128. frag spans k&7; k-gather.
        const int u = T - 65536, e = u >> 12, fid = u & 4095;
        const int blkv = fid >> 6, lane = fid & 63;
        const int k0 = ((blkv & 3) << 5) | ((lane >> 4) << 3);
        const int n  = ((blkv >> 2) << 4) | (lane & 15);
        const float* src = W0 + e * 32768 + n;
        bf16x8 vv;
#pragma unroll
        for (int j = 0; j < 8; ++j) vv[j] = (short)f2bf(src[(k0 + j) * 256]);
        *(bf16x8*)(W0s1 + e * 32768 + (fid << 3)) = vv;
    } else if (T < 98304) {
        // W0s4: row=k(d), col=n(h). frag spans n&7 -> 8 contiguous floats.
        const int u = T - 81920, e = u >> 12, fid = u & 4095;
        const int blkv = fid >> 6, lane = fid & 63;
        const int k  = ((blkv >> 3) << 4) | (lane & 15);
        const int n0 = ((blkv & 7) << 5) | ((lane >> 4) << 3);
        const float* src = W0 + e * 32768 + k * 256 + n0;
        float4 a = *(const float4*)src;
        float4 b = *(const float4*)(src + 4);
        bf16x8 vv;
        vv[0] = (short)f2bf(a.x); vv[1] = (short)f2bf(a.y);
        vv[2] = (short)f2bf(a.z); vv[3] = (short)f2bf(a.w);
        vv[4] = (short)f2bf(b.x); vv[5] = (short)f2bf(b.y);
        vv[6] = (short)f2bf(b.z); vv[7] = (short)f2bf(b.w);
        *(bf16x8*)(W0s4 + e * 32768 + (fid << 3)) = vv;
    }
}

// ---------------------------------------------------------------------------
// K2) MEGA dispatch — R12 config: PCH=3008, wave-scan prefix, stride-40
//     tiles (LDS 40,960 B), Bresenham interleave, uint2 {pack,val} scatter.
// ---------------------------------------------------------------------------
#define CH 1280           // chunk stride in shorts (32*40)
__global__ __launch_bounds__(256, 4) void mega_mlp_bin(
    // fused args
    const float* __restrict__ fp,
    const unsigned short* __restrict__ W0s1,
    const unsigned short* __restrict__ W1s2,
    const unsigned short* __restrict__ W1s3,
    const unsigned short* __restrict__ W0s4,
    const float* __restrict__ b0, const float* __restrict__ b1,
    const float* __restrict__ W2, const float* __restrict__ b2,
    float* __restrict__ o_atom,
    unsigned short* __restrict__ Gb,
    const int* __restrict__ counts, const int* __restrict__ lists,
    // producer args
    const int* __restrict__ rows, const int* __restrict__ cols,
    const float* __restrict__ vals,
    unsigned* __restrict__ pvB,
    int* __restrict__ gcur,
    int* __restrict__ ovfR, int* __restrict__ ovfC, float* __restrict__ ovfV,
    int* __restrict__ ocur) {

    __shared__ __align__(16) char smem[40960];
    const int tid = threadIdx.x;

    // Bresenham split: producers spread evenly through dispatch order.
    const int bid = blockIdx.x;
    const int pA = (bid * NBP) / TOTB;          // producers before bid
    const int pB = ((bid + 1) * NBP) / TOTB;    // producers before bid+1

    if (pB > pA) {
        // =================== COO bin producer (pidx = pA) ===================
        int*   Lr    = (int*)smem;                    // 3008*4 = 12032 B
        int*   Lc    = (int*)(smem + 12032);          // 12032 B
        float* Lv    = (float*)(smem + 24064);        // 12032 B
        int*   hist  = (int*)(smem + 36096);          // 1172 B
        int*   pref  = (int*)(smem + 37268);
        int*   curs  = (int*)(smem + 38440);
        int*   gbase = (int*)(smem + 39612);          // ends at 40784

        const int base = pA * PCH;
        const int lim = (base + PCH <= NNZ) ? PCH : (NNZ - base);

        for (int i = tid; i < CBINS; i += 256) hist[i] = 0;
        __syncthreads();

        // phase 1: stash 3008 entries (3 x int4 groups) + LDS histogram
        i32x4 r[3], c[3];
        fv4   v[3];
        int nvalid[3];
#pragma unroll
        for (int j = 0; j < 3; ++j) {
            const int li = tid * 4 + 1024 * j;
            const int i0 = base + li;
            int nv = lim - li;
            nvalid[j] = nv > 4 ? 4 : (nv < 0 ? 0 : nv);
            if (nvalid[j] == 4) {
                r[j] = __builtin_nontemporal_load((const i32x4*)(rows + i0));
                c[j] = __builtin_nontemporal_load((const i32x4*)(cols + i0));
                v[j] = __builtin_nontemporal_load((const fv4*)(vals + i0));
            } else {
                for (int e2 = 0; e2 < nvalid[j]; ++e2) {
                    r[j][e2] = rows[i0 + e2]; c[j][e2] = cols[i0 + e2];
                    v[j][e2] = vals[i0 + e2];
                }
            }
#pragma unroll
            for (int e2 = 0; e2 < 4; ++e2)
                if (e2 < nvalid[j]) atomicAdd(&hist[c[j][e2] >> 9], 1);
        }
        __syncthreads();

        // phase 2: wave-parallel exclusive prefix over 293 bins
        if (tid < 64) {
            int carry = 0;
#pragma unroll
            for (int cch = 0; cch < 5; ++cch) {
                const int i = cch * 64 + tid;
                const int h = (i < CBINS) ? hist[i] : 0;
                int x = h;
#pragma unroll
                for (int off = 1; off < 64; off <<= 1) {
                    int y = __shfl_up(x, off, 64);
                    if (tid >= off) x += y;
                }
                if (i < CBINS) pref[i] = carry + x - h;   // exclusive
                carry += __shfl(x, 63, 64);
            }
        }
        __syncthreads();
        // phase 2.5: reserve global ranges; init cursors
        for (int b = tid; b < CBINS; b += 256) {
            gbase[b] = atomicAdd(&gcur[b], hist[b]);
            curs[b] = pref[b];
        }
        __syncthreads();

        // phase 3: scatter into LDS (counting-sort order)
#pragma unroll
        for (int j = 0; j < 3; ++j)
#pragma unroll
            for (int e2 = 0; e2 < 4; ++e2)
                if (e2 < nvalid[j]) {
                    int b = c[j][e2] >> 9;
                    int p = atomicAdd(&curs[b], 1);
                    Lr[p] = r[j][e2]; Lc[p] = c[j][e2]; Lv[p] = v[j][e2];
                }
        __syncthreads();

        // phase 4: linear LDS -> global, ONE uint2 {pack,val} per entry
#pragma unroll
        for (int j = 0; j < 12; ++j) {
            const int p = tid + 256 * j;
            if (p >= lim) break;
            const int col = Lc[p];
            const int b = col >> 9;
            const int g = gbase[b] + (p - pref[b]);
            if (g < BCAP) {
                uint2 w;
                w.x = ((unsigned)(col & 511) << 23) | (unsigned)Lr[p];
                w.y = __float_as_uint(Lv[p]);
                *(uint2*)(pvB + (((size_t)b * BCAP + g) << 1)) = w;
            } else {
                int od = atomicAdd(ocur, 1);
                if (od < OCAP) { ovfR[od] = Lr[p]; ovfC[od] = col; ovfV[od] = Lv[p]; }
            }
        }
        return;
    }

    // =================== fused MLP fwd+bwd ===================
    const int fid = bid - pB;
    const int xcd = fid & 7;
    const int e = xcd & 3;
    const int tile = (fid >> 3) * 2 + (xcd >> 2);
    const int cnt = counts[e];
    const int m0 = tile * 32;
    if (m0 >= cnt) return;
    const int* list = lists + e * N_ATOMS;

    short* tH = (short*)smem;                    // 20480 B
    short* tD = (short*)(smem + 20480);          // 20480 B (pads: energy red)

    const int lane = tid & 63;
    const int wv = tid >> 6;       // 0..3, n-range wv*64
    const int lr = lane & 15;
    const int lq = lane >> 4;

    const unsigned short* B1 = W0s1 + (size_t)e * HID * IN_DIM;
    const unsigned short* B2 = W1s2 + (size_t)e * HID * HID;
    const unsigned short* B3 = W1s3 + (size_t)e * HID * HID;
    const unsigned short* B4 = W0s4 + (size_t)e * IN_DIM * HID;

    f32x4 acc[2][4];
#define ZERO_ACC()                                                        \
    _Pragma("unroll") for (int mt = 0; mt < 2; ++mt)                      \
        _Pragma("unroll") for (int nt = 0; nt < 4; ++nt)                  \
            _Pragma("unroll") for (int j = 0; j < 4; ++j) acc[mt][nt][j] = 0.f;

    // ---- S1 A-tile staging ----
    {
        bf16x8 bb0[4];   // hoisted B ki=0 preload (flies during staging)
#pragma unroll
        for (int nt = 0; nt < 4; ++nt)
            bb0[nt] = *(const bf16x8*)(B1 +
                ((size_t)(((wv * 4 + nt) * 4 + 0) * 64 + lane) << 3));

#pragma unroll
        for (int p = 0; p < 4; ++p) {
            const int row = p * 8 + (tid >> 5);
            const int col = (tid & 31) * 4;          // float index in row
            const int m = m0 + row;
            float4 a = make_float4(0.f, 0.f, 0.f, 0.f);
            if (m < cnt)
                a = *(const float4*)(fp + (size_t)list[m] * IN_DIM + col);
            short4 b;
            b.x = (short)f2bf(a.x); b.y = (short)f2bf(a.y);
            b.z = (short)f2bf(a.z); b.w = (short)f2bf(a.w);
            *(short4*)&tD[(col >> 5) * CH + row * 40 + (col & 31)] = b;
        }
        __syncthreads();

        // =============== Stage 1: z0 = A @ W0^T  (K=128, KN=4, B ring-2) ===
        ZERO_ACC();
        bf16x8 bb[2][4];
#pragma unroll
        for (int nt = 0; nt < 4; ++nt) bb[0][nt] = bb0[nt];
#pragma unroll
        for (int ki = 0; ki < 4; ++ki) {
            const int cur = ki & 1, nx = cur ^ 1;
            if (ki < 3) {
#pragma unroll
                for (int nt = 0; nt < 4; ++nt)
                    bb[nx][nt] = *(const bf16x8*)(B1 +
                        ((size_t)(((wv * 4 + nt) * 4 + ki + 1) * 64 + lane) << 3));
            }
            bf16x8 af[2];
#pragma unroll
            for (int mt = 0; mt < 2; ++mt)
                af[mt] = *(const bf16x8*)&tD[ki * CH + (mt * 16 + lr) * 40 + lq * 8];
#pragma unroll
            for (int mt = 0; mt < 2; ++mt)
#pragma unroll
                for (int nt = 0; nt < 4; ++nt)
                    acc[mt][nt] = __builtin_amdgcn_mfma_f32_16x16x32_bf16(
                        af[mt], bb[cur][nt], acc[mt][nt], 0, 0, 0);
        }
    }

    // S2 B-ring preload
    bf16x8 b2r[3][4];
#pragma unroll
    for (int p = 0; p < 3; ++p)
#pragma unroll
        for (int nt = 0; nt < 4; ++nt)
            b2r[p][nt] = *(const bf16x8*)(B2 +
                ((size_t)(((wv * 4 + nt) * 8 + p) * 64 + lane) << 3));

    // epilogue 1: h0 -> tH
    {
        float bv[4];
#pragma unroll
        for (int nt = 0; nt < 4; ++nt)
            bv[nt] = b0[e * HID + wv * 64 + nt * 16 + lr];
#pragma unroll
        for (int mt = 0; mt < 2; ++mt)
#pragma unroll
            for (int rr = 0; rr < 4; ++rr) {
                const int row = mt * 16 + lq * 4 + rr;
#pragma unroll
                for (int nt = 0; nt < 4; ++nt) {
                    const int n = wv * 64 + nt * 16 + lr;
                    float t = tanh_fast(acc[mt][nt][rr] + bv[nt]);
                    tH[(n >> 5) * CH + row * 40 + (n & 31)] = (short)f2bf(t);
                }
            }
    }
    __syncthreads();

    // =============== Stage 2: z1 = h0 @ W1^T   (K=256, ring-3) =============
    ZERO_ACC();
#pragma unroll
    for (int ki = 0; ki < 8; ++ki) {
        bf16x8 af[2];
#pragma unroll
        for (int mt = 0; mt < 2; ++mt)
            af[mt] = *(const bf16x8*)&tH[ki * CH + (mt * 16 + lr) * 40 + lq * 8];
#pragma unroll
        for (int mt = 0; mt < 2; ++mt)
#pragma unroll
            for (int nt = 0; nt < 4; ++nt)
                acc[mt][nt] = __builtin_amdgcn_mfma_f32_16x16x32_bf16(
                    af[mt], b2r[ki % 3][nt], acc[mt][nt], 0, 0, 0);
        if (ki < 5) {
#pragma unroll
            for (int nt = 0; nt < 4; ++nt)
                b2r[ki % 3][nt] = *(const bf16x8*)(B2 +
                    ((size_t)(((wv * 4 + nt) * 8 + ki + 3) * 64 + lane) << 3));
        }
    }

    // S3 B-ring preload
    bf16x8 b3r[3][4];
#pragma unroll
    for (int p = 0; p < 3; ++p)
#pragma unroll
        for (int nt = 0; nt < 4; ++nt)
            b3r[p][nt] = *(const bf16x8*)(B3 +
                ((size_t)(((wv * 4 + nt) * 8 + p) * 64 + lane) << 3));

    // epilogue 2: dz1 -> tD; o partials -> tD chunk-0 pad cols (16 B/row)
    {
        float bv[4], w2v[4];
#pragma unroll
        for (int nt = 0; nt < 4; ++nt) {
            bv[nt]  = b1[e * HID + wv * 64 + nt * 16 + lr];
            w2v[nt] = W2[e * HID + wv * 64 + nt * 16 + lr];
        }
#pragma unroll
        for (int mt = 0; mt < 2; ++mt)
#pragma unroll
            for (int rr = 0; rr < 4; ++rr) {
                const int row = mt * 16 + lq * 4 + rr;
                float osum = 0.f;
#pragma unroll
                for (int nt = 0; nt < 4; ++nt) {
                    const int n = wv * 64 + nt * 16 + lr;
                    float t = tanh_fast(acc[mt][nt][rr] + bv[nt]);
                    osum += t * w2v[nt];
                    tD[(n >> 5) * CH + row * 40 + (n & 31)] =
                        (short)f2bf(w2v[nt] * (1.f - t * t));
                }
                osum += __shfl_xor(osum, 1, 64);
                osum += __shfl_xor(osum, 2, 64);
                osum += __shfl_xor(osum, 4, 64);
                osum += __shfl_xor(osum, 8, 64);
                if (lr == 0)
                    ((float*)&tD[row * 40 + 32])[wv] = osum;   // pad cols 32..39
            }
    }
    __syncthreads();
    if (tid < 32) {
        int m = m0 + tid;
        if (m < cnt) {
            const float4 r4 = *(const float4*)&tD[tid * 40 + 32]; // 16B-aligned
            o_atom[list[m]] = r4.x + r4.y + r4.z + r4.w + b2[e];
        }
    }

    // =============== Stage 3: dh0 = dz1 @ W1   (K=256, ring-3) =============
    ZERO_ACC();
#pragma unroll
    for (int ki = 0; ki < 8; ++ki) {
        bf16x8 af[2];
#pragma unroll
        for (int mt = 0; mt < 2; ++mt)
            af[mt] = *(const bf16x8*)&tD[ki * CH + (mt * 16 + lr) * 40 + lq * 8];
#pragma unroll
        for (int mt = 0; mt < 2; ++mt)
#pragma unroll
            for (int nt = 0; nt < 4; ++nt)
                acc[mt][nt] = __builtin_amdgcn_mfma_f32_16x16x32_bf16(
                    af[mt], b3r[ki % 3][nt], acc[mt][nt], 0, 0, 0);
        if (ki < 5) {
#pragma unroll
            for (int nt = 0; nt < 4; ++nt)
                b3r[ki % 3][nt] = *(const bf16x8*)(B3 +
                    ((size_t)(((wv * 4 + nt) * 8 + ki + 3) * 64 + lane) << 3));
        }
    }

    // S4 B-ring preload
    bf16x8 b4r[3][2];
#pragma unroll
    for (int p = 0; p < 3; ++p)
#pragma unroll
        for (int nt = 0; nt < 2; ++nt)
            b4r[p][nt] = *(const bf16x8*)(B4 +
                ((size_t)(((wv * 2 + nt) * 8 + p) * 64 + lane) << 3));

    // epilogue 3: dz0 = dh0*(1-h0^2) -> tH in-place (same thread owns slot)
#pragma unroll
    for (int mt = 0; mt < 2; ++mt)
#pragma unroll
        for (int rr = 0; rr < 4; ++rr) {
            const int row = mt * 16 + lq * 4 + rr;
#pragma unroll
            for (int nt = 0; nt < 4; ++nt) {
                const int n = wv * 64 + nt * 16 + lr;
                const int a = (n >> 5) * CH + row * 40 + (n & 31);
                float h = bf2f((unsigned short)tH[a]);
                tH[a] = (short)f2bf(acc[mt][nt][rr] * (1.f - h * h));
            }
        }
    __syncthreads();

    // =============== Stage 4: g = dz0 @ W0   (K=256, NT=2, ring-3) =========
    {
        f32x4 a4[2][2];
#pragma unroll
        for (int mt = 0; mt < 2; ++mt)
#pragma unroll
            for (int nt = 0; nt < 2; ++nt)
#pragma unroll
                for (int j = 0; j < 4; ++j) a4[mt][nt][j] = 0.f;
#pragma unroll
        for (int ki = 0; ki < 8; ++ki) {
            bf16x8 af[2];
#pragma unroll
            for (int mt = 0; mt < 2; ++mt)
                af[mt] = *(const bf16x8*)&tH[ki * CH + (mt * 16 + lr) * 40 + lq * 8];
#pragma unroll
            for (int mt = 0; mt < 2; ++mt)
#pragma unroll
                for (int nt = 0; nt < 2; ++nt)
                    a4[mt][nt] = __builtin_amdgcn_mfma_f32_16x16x32_bf16(
                        af[mt], b4r[ki % 3][nt], a4[mt][nt], 0, 0, 0);
            if (ki < 5) {
#pragma unroll
                for (int nt = 0; nt < 2; ++nt)
                    b4r[ki % 3][nt] = *(const bf16x8*)(B4 +
                        ((size_t)(((wv * 2 + nt) * 8 + ki + 3) * 64 + lane) << 3));
            }
        }
        // epilogue 4: g -> tD chunk-major, then coalesced bf16x8 scatter
#pragma unroll
        for (int mt = 0; mt < 2; ++mt)
#pragma unroll
            for (int rr = 0; rr < 4; ++rr) {
                const int row = mt * 16 + lq * 4 + rr;
#pragma unroll
                for (int nt = 0; nt < 2; ++nt) {
                    const int n = wv * 32 + nt * 16 + lr;
                    tD[(n >> 5) * CH + row * 40 + (n & 31)] =
                        (short)f2bf(a4[mt][nt][rr]);
                }
            }
    }
    __syncthreads();
#pragma unroll
    for (int t = 0; t < 2; ++t) {
        const int c = tid + 256 * t;         // 0..511
        const int row = c >> 4;              // 0..31
        const int pos = (c & 15) * 8;        // 0..120
        const int m = m0 + row;
        if (m < cnt) {
            bf16x8 v = *(const bf16x8*)&tD[(pos >> 5) * CH + row * 40 + (pos & 31)];
            *(bf16x8*)(Gb + (size_t)list[m] * IN_DIM + pos) = v;
        }
    }
#undef ZERO_ACC
}

// ---------------------------------------------------------------------------
// K3) Forces consumer — R25: one block per col-window (exclusive ownership),
//     unroll-8 single pass, NT pvB loads, plain F stores. Energy dedicated.
// ---------------------------------------------------------------------------
__global__ __launch_bounds__(1024) void forces_consumer(
    const unsigned* __restrict__ pvB,
    const int* __restrict__ gcur,
    const unsigned short* __restrict__ g, float* __restrict__ F,
    const float* __restrict__ o_atom, const int* __restrict__ img,
    float* __restrict__ energy,
    const int* __restrict__ ovfR, const int* __restrict__ ovfC,
    const float* __restrict__ ovfV, const int* __restrict__ ocur) {

    const int blk = blockIdx.x;
    const int tid = threadIdx.x;

    if (blk < CBINS) {
        __shared__ float win[CW];
        for (int i = tid; i < CW; i += 1024) win[i] = 0.f;
        __syncthreads();
        const int w0 = blk << 9;
        int cnt = gcur[blk]; if (cnt > BCAP) cnt = BCAP;
        const unsigned* base = pvB + (((size_t)blk * BCAP) << 1);
        const int i0 = tid * 8;                 // covers [0, 8192) = BCAP
        if (i0 < cnt) {
            if (i0 + 8 <= cnt) {
                const i32x4* src = (const i32x4*)(base + (i0 << 1));
                i32x4 q0 = __builtin_nontemporal_load(src);
                i32x4 q1 = __builtin_nontemporal_load(src + 1);
                i32x4 q2 = __builtin_nontemporal_load(src + 2);
                i32x4 q3 = __builtin_nontemporal_load(src + 3);
                unsigned pk[8]; float vv[8];
                pk[0] = (unsigned)q0[0]; vv[0] = __uint_as_float(q0[1]);
                pk[1] = (unsigned)q0[2]; vv[1] = __uint_as_float(q0[3]);
                pk[2] = (unsigned)q1[0]; vv[2] = __uint_as_float(q1[1]);
                pk[3] = (unsigned)q1[2]; vv[3] = __uint_as_float(q1[3]);
                pk[4] = (unsigned)q2[0]; vv[4] = __uint_as_float(q2[1]);
                pk[5] = (unsigned)q2[2]; vv[5] = __uint_as_float(q2[3]);
                pk[6] = (unsigned)q3[0]; vv[6] = __uint_as_float(q3[1]);
                pk[7] = (unsigned)q3[2]; vv[7] = __uint_as_float(q3[3]);
                float gv[8];
#pragma unroll
                for (int j = 0; j < 8; ++j)
                    gv[j] = bf2f(g[pk[j] & 0x7FFFFFu]);   // 8 gathers in flight
#pragma unroll
                for (int j = 0; j < 8; ++j)
                    atomicAdd(&win[pk[j] >> 23], -vv[j] * gv[j]);
            } else {
                for (int e2 = i0; e2 < cnt; ++e2) {
                    unsigned pk = base[e2 << 1];
                    float vv = __uint_as_float(base[(e2 << 1) + 1]);
                    atomicAdd(&win[pk >> 23], -vv * bf2f(g[pk & 0x7FFFFFu]));
                }
            }
        }
        // fold overflow entries belonging to this window (expected none)
        {
            int ocnt = ocur[0]; if (ocnt > OCAP) ocnt = OCAP;
            for (int k2 = tid; k2 < ocnt; k2 += 1024) {
                int c = ovfC[k2];
                if (c >= w0 && c < w0 + CW)
                    atomicAdd(&win[c - w0], -ovfV[k2] * bf2f(g[ovfR[k2]]));
            }
        }
        __syncthreads();
        // exclusive window ownership -> plain stores
        for (int i = tid; i < CW; i += 1024) {
            int c = w0 + i;
            if (c < 3 * N_ATOMS) F[c] = win[i];
        }
        return;
    }

    // dedicated energy blocks
    {
        const int bb = blk - CBINS;   // [0, N_IMG)
        int lo, hi;
        {
            int l = 0, r = N_ATOMS;
            while (l < r) { int m = (l + r) >> 1; if (img[m] < bb) l = m + 1; else r = m; }
            lo = l;
        }
        {
            int l = lo, r = N_ATOMS;
            while (l < r) { int m = (l + r) >> 1; if (img[m] < bb + 1) l = m + 1; else r = m; }
            hi = l;
        }
        float s = 0.f;
        for (int i2 = lo + tid; i2 < hi; i2 += 1024) s += o_atom[i2];
#pragma unroll
        for (int off = 32; off > 0; off >>= 1) s += __shfl_down(s, off, 64);
        __shared__ float red[16];
        if ((tid & 63) == 0) red[tid >> 6] = s;
        __syncthreads();
        if (tid == 0) {
            float t = 0.f;
#pragma unroll
            for (int w2 = 0; w2 < 16; ++w2) t += red[w2];
            energy[bb] = t;
        }
    }
}

// ---------------------------------------------------------------------------
extern "C" void kernel_launch(void* const* d_in, const int* in_sizes, int n_in,
                              void* d_out, int out_size, void* d_ws, size_t ws_size,
                              hipStream_t stream) {
    const float* fp    = (const float*)d_in[0];
    const int*   Z     = (const int*)d_in[1];
    const int*   img   = (const int*)d_in[2];
    const int*   frows = (const int*)d_in[3];
    const int*   fcols = (const int*)d_in[4];
    const float* fvals = (const float*)d_in[5];
    const float* W0    = (const float*)d_in[6];
    const float* b0    = (const float*)d_in[7];
    const float* W1    = (const float*)d_in[8];
    const float* b1    = (const float*)d_in[9];
    const float* W2    = (const float*)d_in[10];
    const float* b2    = (const float*)d_in[11];

    float* out    = (float*)d_out;
    float* energy = out;             // [N_IMG]
    float* F      = out + N_IMG;     // [3*N_ATOMS]

    char* ws = (char*)d_ws;
    // counts/gcur/ocur packed contiguously for one memset
    int*   counts = (int*)ws;                          // 16 B @ ws+0
    int*   gcur   = (int*)(ws + 32);                   // 1172 B @ ws+32
    int*   ocur   = (int*)(ws + 32 + 4 * CBINS);       // 4 B @ ws+1204
    int*   lists  = (int*)(ws + 4096);                 // 800 KB
    char*  base   = ws + (1 << 20);
    unsigned short* Gb   = (unsigned short*)(base);              // 12.8 MB (atom order)
    float* o_atom        = (float*)(base + 13000000);            // 200 KB
    unsigned short* W0s1 = (unsigned short*)(base + 14000000);   // 256 KB
    unsigned short* W0s4 = W0s1 + N_ELEM * IN_DIM * HID;
    unsigned short* W1s2 = W0s4 + N_ELEM * IN_DIM * HID;
    unsigned short* W1s3 = W1s2 + N_ELEM * HID * HID;
    unsigned* pvB = (unsigned*)(base + 19000000);                // 19.2 MB interleaved
    int*   ovfR  = (int*)(base + 49000000);
    int*   ovfC  = (int*)(base + 49050000);
    float* ovfV  = (float*)(base + 49100000);

    // memset(counts+gcur+ocur) -> prep||bucket -> mega(bin~mlp) -> consumer
    hipMemsetAsync(ws, 0, 32 + 4 * CBINS + 4, stream);

    prep_and_bucket<<<PREPB + BKB, 256, 0, stream>>>(
        W0, W1, W0s1, W1s2, W1s3, W0s4, Z, counts, lists, F);

    mega_mlp_bin<<<TOTB, 256, 0, stream>>>(
        fp, W0s1, W1s2, W1s3, W0s4, b0, b1, W2, b2, o_atom, Gb, counts, lists,
        frows, fcols, fvals, pvB, gcur, ovfR, ovfC, ovfV, ocur);

    forces_consumer<<<CBINS + N_IMG, 1024, 0, stream>>>(
        pvB, gcur, Gb, F, o_atom, img, energy,
        ovfR, ovfC, ovfV, ocur);
}